// Round 4
// baseline (529.468 us; speedup 1.0000x reference)
//
#include <hip/hip_runtime.h>
#include <hip/hip_bf16.h>
#include <math.h>

// Problem constants
#define BSZ 8
#define LSEQ 512
#define ENC_IN 7
#define D_MODEL 768
#define D_INNER 1536
#define DT_RANK 48
#define N_STATE 16
#define K_CONV 4
#define E_LAYERS 2
#define C_OUT 7
#define PRED_LEN 96
#define EPSV 1e-5f
#define XN 80
#define KSPLIT 4

#define ROWS (BSZ*LSEQ)            // 4096
#define NC 16                      // scan chunks
#define CL (LSEQ/NC)               // 32 steps per chunk
#define LOG2E 1.44269504088896f

typedef __bf16 bf16x8 __attribute__((ext_vector_type(8)));
typedef float  f32x4  __attribute__((ext_vector_type(4)));

// ---------------------------------------------------------------- utilities
__device__ __forceinline__ float block_sum(float v, float* tmp) {
    #pragma unroll
    for (int off = 32; off > 0; off >>= 1) v += __shfl_down(v, off);
    int lane = threadIdx.x & 63, wid = threadIdx.x >> 6;
    __syncthreads();
    if (lane == 0) tmp[wid] = v;
    __syncthreads();
    return tmp[0] + tmp[1] + tmp[2] + tmp[3];
}

// ---------------------------------------------------------------- f32 -> bf16 convert
__global__ __launch_bounds__(256) void cvt_bf16(const float* __restrict__ in,
                                                __hip_bfloat16* __restrict__ out, int n) {
    int i = blockIdx.x*256 + threadIdx.x;
    if (i < n) out[i] = __float2bfloat16(in[i]);
}

// pack src(rows x sld) cols[0:kvalid) into bf16 dst(rows x dld), zero-pad rest
__global__ __launch_bounds__(256) void pack_pad(const float* __restrict__ src, int sld, int kvalid,
                                                __hip_bfloat16* __restrict__ dst, int dld, int rows) {
    int i = blockIdx.x*256 + threadIdx.x;
    int r = i / dld, c = i % dld;
    if (r < rows)
        dst[i] = __float2bfloat16(c < kvalid ? src[(size_t)r*sld + c] : 0.f);
}

// ---------------------------------------------------------------- stats (RevIN)
__global__ __launch_bounds__(256) void stats_kernel(const float* __restrict__ x,
                                                    float* __restrict__ mean,
                                                    float* __restrict__ stdv) {
    int bc = blockIdx.x;
    int b = bc / ENC_IN, c = bc % ENC_IN;
    __shared__ float tmp[4];
    float s = 0.f, sq = 0.f;
    for (int l = threadIdx.x; l < LSEQ; l += 256) {
        float v = x[((size_t)(b*LSEQ + l))*ENC_IN + c];
        s += v; sq += v*v;
    }
    s = block_sum(s, tmp);
    sq = block_sum(sq, tmp);
    if (threadIdx.x == 0) {
        float m = s / LSEQ;
        float var = sq / LSEQ - m*m;
        if (var < 0.f) var = 0.f;
        mean[bc] = m;
        stdv[bc] = sqrtf(var + EPSV);
    }
}

// ---------------------------------------------------------------- embedding
__global__ __launch_bounds__(256) void embed_kernel(const float* __restrict__ x,
                                                    const float* __restrict__ token_w,
                                                    const float* __restrict__ time_w,
                                                    const float* __restrict__ mean,
                                                    const float* __restrict__ stdv,
                                                    float* __restrict__ h) {
    int bl = blockIdx.x;
    int b = bl >> 9, l = bl & 511;
    __shared__ float sxc[ENC_IN*3];
    if (threadIdx.x < ENC_IN*3) {
        int c = threadIdx.x / 3, k = threadIdx.x % 3;
        int lk = (l + k - 1) & 511;
        float v = x[((size_t)(b*LSEQ + lk))*ENC_IN + c];
        sxc[threadIdx.x] = (v - mean[b*ENC_IN + c]) / stdv[b*ENC_IN + c];
    }
    __syncthreads();
    #pragma unroll
    for (int i = 0; i < 3; i++) {
        int d = threadIdx.x + i*256;
        float acc = 0.f;
        const float* w = token_w + (size_t)d*21;
        #pragma unroll
        for (int t = 0; t < 21; t++) acc += sxc[t] * w[t];
        int d2 = d & ~1;
        float div = __expf((float)d2 * (-9.210340371976184f / (float)D_MODEL));
        float ang = (float)l * div;
        float pe = (d & 1) ? cosf(ang) : sinf(ang);
        float tm = ((float)l / (float)LSEQ) * time_w[d];
        h[(size_t)bl*D_MODEL + d] = acc + pe + tm;
    }
}

// ---------------------------------------------------------------- rmsnorm -> bf16
__global__ __launch_bounds__(256) void rmsnorm_bf16(const float* __restrict__ h,
                                                    const float* __restrict__ w,
                                                    __hip_bfloat16* __restrict__ xn) {
    size_t base = (size_t)blockIdx.x * D_MODEL;
    __shared__ float tmp[4];
    float ss = 0.f;
    for (int k = threadIdx.x; k < D_MODEL; k += 256) { float v = h[base+k]; ss += v*v; }
    ss = block_sum(ss, tmp);
    float inv = rsqrtf(ss / (float)D_MODEL + EPSV);
    for (int k = threadIdx.x; k < D_MODEL; k += 256)
        xn[base+k] = __float2bfloat16(h[base+k]*inv*w[k]);
}

// ---------------------------------------------------------------- bf16 MFMA GEMM (128x128 tile, BK=32)
// C(M x N) = A(M x K) @ Bw(N x K)^T.  XOR-swizzled LDS.
// FUSE 0: plain   FUSE 1: softplus(acc+bias[n])   FUSE 2: acc + res
// FUSE 3: split output: col < D_INNER -> C, else -> C2 (both compact, ld = D_INNER)
template<int FUSE>
__global__ __launch_bounds__(256) void gemm_mfma(const __hip_bfloat16* __restrict__ A,
                                                 const __hip_bfloat16* __restrict__ Bw,
                                                 float* __restrict__ C, int ldc,
                                                 int K,
                                                 const float* __restrict__ bias,
                                                 const float* __restrict__ res, int ldr,
                                                 float* __restrict__ C2) {
    __shared__ __align__(16) __hip_bfloat16 As[128*32];
    __shared__ __align__(16) __hip_bfloat16 Bs[128*32];
    int tid = threadIdx.x, lane = tid & 63, w = tid >> 6;
    int m0 = blockIdx.y * 128, n0 = blockIdx.x * 128;
    int wr = w >> 1, wc = w & 1;
    int kq = lane >> 4, rr = lane & 15;

    f32x4 acc[4][4];
    #pragma unroll
    for (int i = 0; i < 4; i++)
        #pragma unroll
        for (int j = 0; j < 4; j++) acc[i][j] = (f32x4){0.f,0.f,0.f,0.f};

    const char* Ab = (const char*)A;
    const char* Bb = (const char*)Bw;
    char* AsB = (char*)As;
    char* BsB = (char*)Bs;

    int c0 = tid, c1 = tid + 256;
    int r0 = c0 >> 2, q0 = (c0 & 3) ^ ((r0 >> 1) & 3);   // swizzled chunk
    int r1 = c1 >> 2, q1 = (c1 & 3) ^ ((r1 >> 1) & 3);
    int sw = (kq ^ ((rr >> 1) & 3)) * 16;                // swizzled read byte offset

    for (int k0 = 0; k0 < K; k0 += 32) {
        __builtin_amdgcn_global_load_lds(
            (const __attribute__((address_space(1))) unsigned int*)(Ab + ((size_t)(m0+r0)*K + k0 + q0*8)*2),
            (__attribute__((address_space(3))) unsigned int*)(AsB + c0*16), 16, 0, 0);
        __builtin_amdgcn_global_load_lds(
            (const __attribute__((address_space(1))) unsigned int*)(Ab + ((size_t)(m0+r1)*K + k0 + q1*8)*2),
            (__attribute__((address_space(3))) unsigned int*)(AsB + c1*16), 16, 0, 0);
        __builtin_amdgcn_global_load_lds(
            (const __attribute__((address_space(1))) unsigned int*)(Bb + ((size_t)(n0+r0)*K + k0 + q0*8)*2),
            (__attribute__((address_space(3))) unsigned int*)(BsB + c0*16), 16, 0, 0);
        __builtin_amdgcn_global_load_lds(
            (const __attribute__((address_space(1))) unsigned int*)(Bb + ((size_t)(n0+r1)*K + k0 + q1*8)*2),
            (__attribute__((address_space(3))) unsigned int*)(BsB + c1*16), 16, 0, 0);
        __syncthreads();

        bf16x8 af[4], bfr[4];
        #pragma unroll
        for (int mi = 0; mi < 4; mi++) af[mi]  = *(const bf16x8*)(AsB + (wr*64 + mi*16 + rr)*64 + sw);
        #pragma unroll
        for (int ni = 0; ni < 4; ni++) bfr[ni] = *(const bf16x8*)(BsB + (wc*64 + ni*16 + rr)*64 + sw);
        #pragma unroll
        for (int mi = 0; mi < 4; mi++)
            #pragma unroll
            for (int ni = 0; ni < 4; ni++)
                acc[mi][ni] = __builtin_amdgcn_mfma_f32_16x16x32_bf16(af[mi], bfr[ni], acc[mi][ni], 0, 0, 0);
        __syncthreads();
    }

    #pragma unroll
    for (int mi = 0; mi < 4; mi++) {
        #pragma unroll
        for (int ni = 0; ni < 4; ni++) {
            #pragma unroll
            for (int r = 0; r < 4; r++) {
                int row = m0 + wr*64 + mi*16 + kq*4 + r;
                int col = n0 + wc*64 + ni*16 + rr;
                float v = acc[mi][ni][r];
                if (FUSE == 1) { v += bias[col]; v = fmaxf(v, 0.f) + log1pf(__expf(-fabsf(v))); }
                if (FUSE == 2) v += res[(size_t)row*ldr + col];
                if (FUSE == 3) {
                    if (col < D_INNER) C[(size_t)row*D_INNER + col] = v;
                    else               C2[(size_t)row*D_INNER + col - D_INNER] = v;
                } else {
                    C[(size_t)row*ldc + col] = v;
                }
            }
        }
    }
}

// ---------------------------------------------------------------- xproj MFMA: C(4096 x 80) += A @ W^T, split-K
__global__ __launch_bounds__(256) void gemm_xproj(const __hip_bfloat16* __restrict__ A,
                                                  const __hip_bfloat16* __restrict__ W,
                                                  float* __restrict__ C) {
    __shared__ __align__(16) __hip_bfloat16 As[64*64];
    __shared__ __align__(16) __hip_bfloat16 Bs[96*64];
    int tid = threadIdx.x, lane = tid & 63, w = tid >> 6;
    int m0 = blockIdx.x * 64;
    int k0 = blockIdx.y * (D_INNER / KSPLIT);
    int kq = lane >> 4, rr = lane & 15;
    f32x4 acc[5];
    #pragma unroll
    for (int i = 0; i < 5; i++) acc[i] = (f32x4){0.f,0.f,0.f,0.f};
    const char* Ab = (const char*)A;
    const char* Wb = (const char*)W;
    char* AsB = (char*)As;
    char* BsB = (char*)Bs;

    for (int kk = k0; kk < k0 + D_INNER/KSPLIT; kk += 64) {
        #pragma unroll
        for (int cA = 0; cA < 2; cA++) {
            int idx = cA*256 + tid;
            int r = idx >> 3, q = (idx & 7) ^ (r & 7);
            __builtin_amdgcn_global_load_lds(
                (const __attribute__((address_space(1))) unsigned int*)(Ab + ((size_t)(m0+r)*D_INNER + kk + q*8)*2),
                (__attribute__((address_space(3))) unsigned int*)(AsB + idx*16), 16, 0, 0);
        }
        #pragma unroll
        for (int cB = 0; cB < 3; cB++) {
            int idx = cB*256 + tid;
            int r = idx >> 3, q = (idx & 7) ^ (r & 7);
            int rs = r < XN ? r : XN-1;
            __builtin_amdgcn_global_load_lds(
                (const __attribute__((address_space(1))) unsigned int*)(Wb + ((size_t)rs*D_INNER + kk + q*8)*2),
                (__attribute__((address_space(3))) unsigned int*)(BsB + idx*16), 16, 0, 0);
        }
        __syncthreads();
        #pragma unroll
        for (int kh = 0; kh < 2; kh++) {
            bf16x8 a = *(const bf16x8*)(AsB + (w*16 + rr)*128 + (((kh*4 + kq) ^ (rr & 7)))*16);
            #pragma unroll
            for (int ni = 0; ni < 5; ni++) {
                bf16x8 b = *(const bf16x8*)(BsB + (ni*16 + rr)*128 + (((kh*4 + kq) ^ (rr & 7)))*16);
                acc[ni] = __builtin_amdgcn_mfma_f32_16x16x32_bf16(a, b, acc[ni], 0, 0, 0);
            }
        }
        __syncthreads();
    }
    #pragma unroll
    for (int ni = 0; ni < 5; ni++)
        #pragma unroll
        for (int r = 0; r < 4; r++) {
            int row = m0 + w*16 + kq*4 + r;
            int col = ni*16 + rr;
            atomicAdd(&C[(size_t)row*XN + col], acc[ni][r]);
        }
}

// ---------------------------------------------------------------- depthwise causal conv + SiLU (+ bf16 copy)
// xs is compact (ROWS x D_INNER)
__global__ __launch_bounds__(256) void dwconv_silu(const float* __restrict__ xs,
                                                   const float* __restrict__ cw,
                                                   const float* __restrict__ cb,
                                                   float* __restrict__ u,
                                                   __hip_bfloat16* __restrict__ u_bf) {
    int idx = blockIdx.x*256 + threadIdx.x;
    if (idx >= ROWS*D_INNER) return;
    int d = idx % D_INNER;
    int t = idx / D_INNER;
    int l = t & 511, b = t >> 9;
    float acc = cb[d];
    #pragma unroll
    for (int k = 0; k < K_CONV; k++) {
        int ll = l - (K_CONV-1) + k;
        if (ll >= 0) acc += xs[((size_t)(b*LSEQ + ll))*D_INNER + d] * cw[d*K_CONV + k];
    }
    float v = acc / (1.f + __expf(-acc));
    u[(size_t)t*D_INNER + d] = v;
    u_bf[(size_t)t*D_INNER + d] = __float2bfloat16(v);
}

// ---------------------------------------------------------------- selective scan, 3-phase chunked (NC=16, CL=32)
__global__ __launch_bounds__(256) void scan_p1(const float* __restrict__ u,
                                               const float* __restrict__ delta,
                                               const float* __restrict__ xdbl,
                                               const float* __restrict__ A_log,
                                               float* __restrict__ xfin,
                                               float* __restrict__ sumdlt) {
    int d = blockIdx.x*256 + threadIdx.x;
    int c = blockIdx.y, b = blockIdx.z;
    int l0 = c*CL;
    __shared__ float sB[CL][16];
    for (int t = threadIdx.x; t < CL*16; t += 256) {
        int i = t >> 4, n = t & 15;
        sB[i][n] = xdbl[((size_t)(b*LSEQ + l0 + i))*XN + DT_RANK + n];
    }
    float A[N_STATE], xs[N_STATE];
    const float* al = A_log + d*N_STATE;
    #pragma unroll
    for (int n = 0; n < N_STATE; n++) {
        A[n] = -__expf(al[n]) * LOG2E;
        xs[n] = 0.f;
    }
    __syncthreads();
    const float* pd = delta + (size_t)(b*LSEQ + l0)*D_INNER + d;
    const float* pu = u     + (size_t)(b*LSEQ + l0)*D_INNER + d;
    float sd = 0.f;
    for (int i = 0; i < CL; i++) {
        float dlt = *pd; pd += D_INNER;
        float uu  = *pu; pu += D_INNER;
        float du = dlt*uu;
        sd += dlt;
        #pragma unroll
        for (int n = 0; n < N_STATE; n++)
            xs[n] = exp2f(dlt*A[n])*xs[n] + du*sB[i][n];
    }
    size_t j = ((size_t)(b*NC + c)*D_INNER + d);
    #pragma unroll
    for (int n = 0; n < N_STATE; n += 4)
        *(float4*)&xfin[j*N_STATE + n] = (float4){xs[n],xs[n+1],xs[n+2],xs[n+3]};
    sumdlt[j] = sd;
}

__global__ __launch_bounds__(256) void scan_p2(const float* __restrict__ xfin,
                                               const float* __restrict__ sumdlt,
                                               const float* __restrict__ A_log,
                                               float* __restrict__ carry) {
    int idx = blockIdx.x*256 + threadIdx.x;
    int n = idx & 15;
    int rest = idx >> 4;
    int d = rest % D_INNER;
    int b = rest / D_INNER;
    float A2 = -__expf(A_log[d*N_STATE + n]) * LOG2E;
    float cr = 0.f;
    carry[((size_t)(b*NC + 0)*D_INNER + d)*N_STATE + n] = 0.f;
    for (int c = 1; c < NC; c++) {
        size_t j = (size_t)(b*NC + c - 1)*D_INNER + d;
        cr = exp2f(A2 * sumdlt[j]) * cr + xfin[j*N_STATE + n];
        carry[((size_t)(b*NC + c)*D_INNER + d)*N_STATE + n] = cr;
    }
}

__global__ __launch_bounds__(256) void scan_p3(const float* __restrict__ u,
                                               const float* __restrict__ delta,
                                               const float* __restrict__ xdbl,
                                               const float* __restrict__ A_log,
                                               const float* __restrict__ Dp,
                                               const float* __restrict__ carry,
                                               const float* __restrict__ res,
                                               __hip_bfloat16* __restrict__ ygate) {
    int d = blockIdx.x*256 + threadIdx.x;
    int c = blockIdx.y, b = blockIdx.z;
    int l0 = c*CL;
    __shared__ float sB[CL][16];
    __shared__ float sC[CL][16];
    for (int t = threadIdx.x; t < CL*16; t += 256) {
        int i = t >> 4, n = t & 15;
        size_t base = ((size_t)(b*LSEQ + l0 + i))*XN + DT_RANK;
        sB[i][n] = xdbl[base + n];
        sC[i][n] = xdbl[base + N_STATE + n];
    }
    float A[N_STATE], xs[N_STATE];
    size_t jc = ((size_t)(b*NC + c)*D_INNER + d)*N_STATE;
    const float* al = A_log + d*N_STATE;
    #pragma unroll
    for (int n = 0; n < N_STATE; n++) {
        A[n] = -__expf(al[n]) * LOG2E;
        xs[n] = carry[jc + n];
    }
    __syncthreads();
    float Dv = Dp[d];
    const float* pd = delta + (size_t)(b*LSEQ + l0)*D_INNER + d;
    const float* pu = u     + (size_t)(b*LSEQ + l0)*D_INNER + d;
    const float* pr = res   + (size_t)(b*LSEQ + l0)*D_INNER + d;
    __hip_bfloat16* py = ygate + (size_t)(b*LSEQ + l0)*D_INNER + d;
    for (int i = 0; i < CL; i++) {
        float dlt = *pd; pd += D_INNER;
        float uu  = *pu; pu += D_INNER;
        float r   = *pr; pr += D_INNER;
        float du = dlt*uu;
        float acc = 0.f;
        #pragma unroll
        for (int n = 0; n < N_STATE; n++) {
            xs[n] = exp2f(dlt*A[n])*xs[n] + du*sB[i][n];
            acc += xs[n]*sC[i][n];
        }
        float y = acc + uu*Dv;
        float g = y * (r / (1.f + __expf(-r)));
        *py = __float2bfloat16(g); py += D_INNER;
    }
}

// ---------------------------------------------------------------- final norm + head + de-norm
__global__ __launch_bounds__(256) void final_kernel(const float* __restrict__ h,
                                                    const float* __restrict__ fnw,
                                                    const float* __restrict__ out_w,
                                                    const float* __restrict__ mean,
                                                    const float* __restrict__ stdv,
                                                    float* __restrict__ out) {
    int bid = blockIdx.x;
    int b = bid / PRED_LEN, lo = bid % PRED_LEN;
    int l = LSEQ - PRED_LEN + lo;
    const float* row = h + ((size_t)(b*LSEQ + l))*D_MODEL;
    __shared__ float tmp[4];
    float ss = 0.f;
    for (int k = threadIdx.x; k < D_MODEL; k += 256) { float v = row[k]; ss += v*v; }
    ss = block_sum(ss, tmp);
    float inv = rsqrtf(ss / (float)D_MODEL + EPSV);
    float acc[C_OUT] = {};
    for (int k = threadIdx.x; k < D_MODEL; k += 256) {
        float hn = row[k]*fnw[k];
        #pragma unroll
        for (int c = 0; c < C_OUT; c++) acc[c] += hn*out_w[c*D_MODEL + k];
    }
    #pragma unroll
    for (int c = 0; c < C_OUT; c++) {
        float s = block_sum(acc[c], tmp);
        if (threadIdx.x == 0)
            out[((size_t)(b*PRED_LEN + lo))*C_OUT + c] = s*inv*stdv[b*ENC_IN + c] + mean[b*ENC_IN + c];
    }
}

// ---------------------------------------------------------------- launch
extern "C" void kernel_launch(void* const* d_in, const int* in_sizes, int n_in,
                              void* d_out, int out_size, void* d_ws, size_t ws_size,
                              hipStream_t stream) {
    const float* x        = (const float*)d_in[0];
    const float* token_w  = (const float*)d_in[1];
    const float* time_w   = (const float*)d_in[2];
    const float* norm_w   = (const float*)d_in[3];
    const float* in_w     = (const float*)d_in[4];
    const float* conv_w   = (const float*)d_in[5];
    const float* conv_b   = (const float*)d_in[6];
    const float* xproj_w  = (const float*)d_in[7];
    const float* dtproj_w = (const float*)d_in[8];
    const float* dtproj_b = (const float*)d_in[9];
    const float* A_log    = (const float*)d_in[10];
    const float* Dp       = (const float*)d_in[11];
    const float* outproj_w= (const float*)d_in[12];
    const float* final_nw = (const float*)d_in[13];
    const float* out_w    = (const float*)d_in[14];
    float* out = (float*)d_out;

    float* ws   = (float*)d_ws;
    float* mean = ws;
    float* stdv = ws + 64;
    float* h    = ws + 128;
    float* xs   = h    + (size_t)ROWS*D_MODEL;       // ROWS*D_INNER (reused: xfin+carry)
    float* res  = xs   + (size_t)ROWS*D_INNER;       // ROWS*D_INNER
    float* u    = res  + (size_t)ROWS*D_INNER;       // ROWS*D_INNER
    float* xdbl = u    + (size_t)ROWS*D_INNER;       // ROWS*80
    float* delta= xdbl + (size_t)ROWS*XN;            // ROWS*D_INNER
    float* sumd = delta+ (size_t)ROWS*D_INNER;       // BSZ*NC*D_INNER
    float* fend = sumd + (size_t)BSZ*NC*D_INNER;
    // aliases into dead xs region (xs consumed by dwconv before scan_p1 runs)
    float* xfin = xs;                                          // BSZ*NC*D_INNER*N_STATE = 3.15M
    float* carry= xs + (size_t)BSZ*NC*D_INNER*N_STATE;         // 3.15M  (exactly fills xs)
    __hip_bfloat16* xn_bf  = (__hip_bfloat16*)fend;
    __hip_bfloat16* ygate  = xn_bf + (size_t)ROWS*D_MODEL;
    __hip_bfloat16* inw_bf = ygate + (size_t)ROWS*D_INNER;
    __hip_bfloat16* outw_bf= inw_bf + (size_t)E_LAYERS*2*D_INNER*D_MODEL;
    __hip_bfloat16* xpw_bf = outw_bf+ (size_t)E_LAYERS*D_MODEL*D_INNER;
    __hip_bfloat16* u_bf   = xpw_bf + (size_t)E_LAYERS*XN*D_INNER;
    __hip_bfloat16* xdbl_bf= u_bf   + (size_t)ROWS*D_INNER;          // 4096 x 64
    __hip_bfloat16* dtw_bf = xdbl_bf+ (size_t)ROWS*64;               // E_LAYERS x 1536 x 64

    // convert weights to bf16 (once per call)
    {
        int n1 = E_LAYERS*2*D_INNER*D_MODEL;
        cvt_bf16<<<(n1+255)/256, 256, 0, stream>>>(in_w, inw_bf, n1);
        int n2 = E_LAYERS*D_MODEL*D_INNER;
        cvt_bf16<<<(n2+255)/256, 256, 0, stream>>>(outproj_w, outw_bf, n2);
        int n3 = E_LAYERS*XN*D_INNER;
        cvt_bf16<<<(n3+255)/256, 256, 0, stream>>>(xproj_w, xpw_bf, n3);
        // dtproj weights for both layers: [2*1536][48] -> [2*1536][64] zero-padded
        pack_pad<<<(E_LAYERS*D_INNER*64+255)/256, 256, 0, stream>>>(
            dtproj_w, DT_RANK, DT_RANK, dtw_bf, 64, E_LAYERS*D_INNER);
    }

    stats_kernel<<<BSZ*ENC_IN, 256, 0, stream>>>(x, mean, stdv);
    embed_kernel<<<ROWS, 256, 0, stream>>>(x, token_w, time_w, mean, stdv, h);

    for (int e = 0; e < E_LAYERS; e++) {
        rmsnorm_bf16<<<ROWS, 256, 0, stream>>>(h, norm_w + e*D_MODEL, xn_bf);
        gemm_mfma<3><<<dim3(2*D_INNER/128, ROWS/128), 256, 0, stream>>>(
            xn_bf, inw_bf + (size_t)e*2*D_INNER*D_MODEL, xs, D_INNER, D_MODEL,
            nullptr, nullptr, 0, res);
        dwconv_silu<<<(ROWS*D_INNER + 255)/256, 256, 0, stream>>>(
            xs, conv_w + (size_t)e*D_INNER*K_CONV, conv_b + e*D_INNER, u, u_bf);
        hipMemsetAsync(xdbl, 0, (size_t)ROWS*XN*sizeof(float), stream);
        gemm_xproj<<<dim3(ROWS/64, KSPLIT), 256, 0, stream>>>(
            u_bf, xpw_bf + (size_t)e*XN*D_INNER, xdbl);
        pack_pad<<<(ROWS*64+255)/256, 256, 0, stream>>>(xdbl, XN, DT_RANK, xdbl_bf, 64, ROWS);
        gemm_mfma<1><<<dim3(D_INNER/128, ROWS/128), 256, 0, stream>>>(
            xdbl_bf, dtw_bf + (size_t)e*D_INNER*64, delta, D_INNER, 64,
            dtproj_b + e*D_INNER, nullptr, 0, nullptr);
        const float* Alog_e = A_log + (size_t)e*D_INNER*N_STATE;
        scan_p1<<<dim3(D_INNER/256, NC, BSZ), 256, 0, stream>>>(
            u, delta, xdbl, Alog_e, xfin, sumd);
        scan_p2<<<(BSZ*D_INNER*N_STATE)/256, 256, 0, stream>>>(
            xfin, sumd, Alog_e, carry);
        scan_p3<<<dim3(D_INNER/256, NC, BSZ), 256, 0, stream>>>(
            u, delta, xdbl, Alog_e, Dp + (size_t)e*D_INNER, carry, res, ygate);
        gemm_mfma<2><<<dim3(D_MODEL/128, ROWS/128), 256, 0, stream>>>(
            ygate, outw_bf + (size_t)e*D_MODEL*D_INNER, h, D_MODEL, D_INNER,
            nullptr, h, D_MODEL, nullptr);
    }

    final_kernel<<<BSZ*PRED_LEN, 256, 0, stream>>>(h, final_nw, out_w, mean, stdv, out);
}

// Round 5
// 521.666 us; speedup vs baseline: 1.0150x; 1.0150x over previous
//
#include <hip/hip_runtime.h>
#include <hip/hip_bf16.h>
#include <math.h>

// Problem constants
#define BSZ 8
#define LSEQ 512
#define ENC_IN 7
#define D_MODEL 768
#define D_INNER 1536
#define DT_RANK 48
#define N_STATE 16
#define K_CONV 4
#define E_LAYERS 2
#define C_OUT 7
#define PRED_LEN 96
#define EPSV 1e-5f
#define XN 80
#define KSPLIT 4

#define ROWS (BSZ*LSEQ)            // 4096
#define NC 32                      // scan chunks
#define CL (LSEQ/NC)               // 16 steps per chunk
#define LOG2E 1.44269504088896f

typedef __bf16 bf16x8 __attribute__((ext_vector_type(8)));
typedef float  f32x4  __attribute__((ext_vector_type(4)));

// ---------------------------------------------------------------- utilities
__device__ __forceinline__ float block_sum(float v, float* tmp) {
    #pragma unroll
    for (int off = 32; off > 0; off >>= 1) v += __shfl_down(v, off);
    int lane = threadIdx.x & 63, wid = threadIdx.x >> 6;
    __syncthreads();
    if (lane == 0) tmp[wid] = v;
    __syncthreads();
    return tmp[0] + tmp[1] + tmp[2] + tmp[3];
}

// ---------------------------------------------------------------- f32 -> bf16 convert
__global__ __launch_bounds__(256) void cvt_bf16(const float* __restrict__ in,
                                                __hip_bfloat16* __restrict__ out, int n) {
    int i = blockIdx.x*256 + threadIdx.x;
    if (i < n) out[i] = __float2bfloat16(in[i]);
}

// pack src(rows x sld) cols[0:kvalid) into bf16 dst(rows x dld), zero-pad rest
__global__ __launch_bounds__(256) void pack_pad(const float* __restrict__ src, int sld, int kvalid,
                                                __hip_bfloat16* __restrict__ dst, int dld, int rows) {
    int i = blockIdx.x*256 + threadIdx.x;
    int r = i / dld, c = i % dld;
    if (r < rows)
        dst[i] = __float2bfloat16(c < kvalid ? src[(size_t)r*sld + c] : 0.f);
}

// ---------------------------------------------------------------- stats (RevIN)
__global__ __launch_bounds__(256) void stats_kernel(const float* __restrict__ x,
                                                    float* __restrict__ mean,
                                                    float* __restrict__ stdv) {
    int bc = blockIdx.x;
    int b = bc / ENC_IN, c = bc % ENC_IN;
    __shared__ float tmp[4];
    float s = 0.f, sq = 0.f;
    for (int l = threadIdx.x; l < LSEQ; l += 256) {
        float v = x[((size_t)(b*LSEQ + l))*ENC_IN + c];
        s += v; sq += v*v;
    }
    s = block_sum(s, tmp);
    sq = block_sum(sq, tmp);
    if (threadIdx.x == 0) {
        float m = s / LSEQ;
        float var = sq / LSEQ - m*m;
        if (var < 0.f) var = 0.f;
        mean[bc] = m;
        stdv[bc] = sqrtf(var + EPSV);
    }
}

// ---------------------------------------------------------------- embedding
__global__ __launch_bounds__(256) void embed_kernel(const float* __restrict__ x,
                                                    const float* __restrict__ token_w,
                                                    const float* __restrict__ time_w,
                                                    const float* __restrict__ mean,
                                                    const float* __restrict__ stdv,
                                                    float* __restrict__ h) {
    int bl = blockIdx.x;
    int b = bl >> 9, l = bl & 511;
    __shared__ float sxc[ENC_IN*3];
    if (threadIdx.x < ENC_IN*3) {
        int c = threadIdx.x / 3, k = threadIdx.x % 3;
        int lk = (l + k - 1) & 511;
        float v = x[((size_t)(b*LSEQ + lk))*ENC_IN + c];
        sxc[threadIdx.x] = (v - mean[b*ENC_IN + c]) / stdv[b*ENC_IN + c];
    }
    __syncthreads();
    #pragma unroll
    for (int i = 0; i < 3; i++) {
        int d = threadIdx.x + i*256;
        float acc = 0.f;
        const float* w = token_w + (size_t)d*21;
        #pragma unroll
        for (int t = 0; t < 21; t++) acc += sxc[t] * w[t];
        int d2 = d & ~1;
        float div = __expf((float)d2 * (-9.210340371976184f / (float)D_MODEL));
        float ang = (float)l * div;
        float pe = (d & 1) ? cosf(ang) : sinf(ang);
        float tm = ((float)l / (float)LSEQ) * time_w[d];
        h[(size_t)bl*D_MODEL + d] = acc + pe + tm;
    }
}

// ---------------------------------------------------------------- rmsnorm -> bf16
__global__ __launch_bounds__(256) void rmsnorm_bf16(const float* __restrict__ h,
                                                    const float* __restrict__ w,
                                                    __hip_bfloat16* __restrict__ xn) {
    size_t base = (size_t)blockIdx.x * D_MODEL;
    __shared__ float tmp[4];
    float ss = 0.f;
    for (int k = threadIdx.x; k < D_MODEL; k += 256) { float v = h[base+k]; ss += v*v; }
    ss = block_sum(ss, tmp);
    float inv = rsqrtf(ss / (float)D_MODEL + EPSV);
    for (int k = threadIdx.x; k < D_MODEL; k += 256)
        xn[base+k] = __float2bfloat16(h[base+k]*inv*w[k]);
}

// ---------------------------------------------------------------- bf16 MFMA GEMM (128x128 tile, BK=32)
// C(M x N) = A(M x K) @ Bw(N x K)^T.  XOR-swizzled LDS.
// FUSE 0: plain   FUSE 1: softplus(acc+bias[n])   FUSE 2: acc + res
// FUSE 3: split output: col < D_INNER -> C, else -> C2 (both compact, ld = D_INNER)
template<int FUSE>
__global__ __launch_bounds__(256) void gemm_mfma(const __hip_bfloat16* __restrict__ A,
                                                 const __hip_bfloat16* __restrict__ Bw,
                                                 float* __restrict__ C, int ldc,
                                                 int K,
                                                 const float* __restrict__ bias,
                                                 const float* __restrict__ res, int ldr,
                                                 float* __restrict__ C2) {
    __shared__ __align__(16) __hip_bfloat16 As[128*32];
    __shared__ __align__(16) __hip_bfloat16 Bs[128*32];
    int tid = threadIdx.x, lane = tid & 63, w = tid >> 6;
    int m0 = blockIdx.y * 128, n0 = blockIdx.x * 128;
    int wr = w >> 1, wc = w & 1;
    int kq = lane >> 4, rr = lane & 15;

    f32x4 acc[4][4];
    #pragma unroll
    for (int i = 0; i < 4; i++)
        #pragma unroll
        for (int j = 0; j < 4; j++) acc[i][j] = (f32x4){0.f,0.f,0.f,0.f};

    const char* Ab = (const char*)A;
    const char* Bb = (const char*)Bw;
    char* AsB = (char*)As;
    char* BsB = (char*)Bs;

    int c0 = tid, c1 = tid + 256;
    int r0 = c0 >> 2, q0 = (c0 & 3) ^ ((r0 >> 1) & 3);   // swizzled chunk
    int r1 = c1 >> 2, q1 = (c1 & 3) ^ ((r1 >> 1) & 3);
    int sw = (kq ^ ((rr >> 1) & 3)) * 16;                // swizzled read byte offset

    for (int k0 = 0; k0 < K; k0 += 32) {
        __builtin_amdgcn_global_load_lds(
            (const __attribute__((address_space(1))) unsigned int*)(Ab + ((size_t)(m0+r0)*K + k0 + q0*8)*2),
            (__attribute__((address_space(3))) unsigned int*)(AsB + c0*16), 16, 0, 0);
        __builtin_amdgcn_global_load_lds(
            (const __attribute__((address_space(1))) unsigned int*)(Ab + ((size_t)(m0+r1)*K + k0 + q1*8)*2),
            (__attribute__((address_space(3))) unsigned int*)(AsB + c1*16), 16, 0, 0);
        __builtin_amdgcn_global_load_lds(
            (const __attribute__((address_space(1))) unsigned int*)(Bb + ((size_t)(n0+r0)*K + k0 + q0*8)*2),
            (__attribute__((address_space(3))) unsigned int*)(BsB + c0*16), 16, 0, 0);
        __builtin_amdgcn_global_load_lds(
            (const __attribute__((address_space(1))) unsigned int*)(Bb + ((size_t)(n0+r1)*K + k0 + q1*8)*2),
            (__attribute__((address_space(3))) unsigned int*)(BsB + c1*16), 16, 0, 0);
        __syncthreads();

        bf16x8 af[4], bfr[4];
        #pragma unroll
        for (int mi = 0; mi < 4; mi++) af[mi]  = *(const bf16x8*)(AsB + (wr*64 + mi*16 + rr)*64 + sw);
        #pragma unroll
        for (int ni = 0; ni < 4; ni++) bfr[ni] = *(const bf16x8*)(BsB + (wc*64 + ni*16 + rr)*64 + sw);
        #pragma unroll
        for (int mi = 0; mi < 4; mi++)
            #pragma unroll
            for (int ni = 0; ni < 4; ni++)
                acc[mi][ni] = __builtin_amdgcn_mfma_f32_16x16x32_bf16(af[mi], bfr[ni], acc[mi][ni], 0, 0, 0);
        __syncthreads();
    }

    #pragma unroll
    for (int mi = 0; mi < 4; mi++) {
        #pragma unroll
        for (int ni = 0; ni < 4; ni++) {
            #pragma unroll
            for (int r = 0; r < 4; r++) {
                int row = m0 + wr*64 + mi*16 + kq*4 + r;
                int col = n0 + wc*64 + ni*16 + rr;
                float v = acc[mi][ni][r];
                if (FUSE == 1) { v += bias[col]; v = fmaxf(v, 0.f) + log1pf(__expf(-fabsf(v))); }
                if (FUSE == 2) v += res[(size_t)row*ldr + col];
                if (FUSE == 3) {
                    if (col < D_INNER) C[(size_t)row*D_INNER + col] = v;
                    else               C2[(size_t)row*D_INNER + col - D_INNER] = v;
                } else {
                    C[(size_t)row*ldc + col] = v;
                }
            }
        }
    }
}

// ---------------------------------------------------------------- xproj MFMA: C(4096 x 80) += A @ W^T, split-K
__global__ __launch_bounds__(256) void gemm_xproj(const __hip_bfloat16* __restrict__ A,
                                                  const __hip_bfloat16* __restrict__ W,
                                                  float* __restrict__ C) {
    __shared__ __align__(16) __hip_bfloat16 As[64*64];
    __shared__ __align__(16) __hip_bfloat16 Bs[96*64];
    int tid = threadIdx.x, lane = tid & 63, w = tid >> 6;
    int m0 = blockIdx.x * 64;
    int k0 = blockIdx.y * (D_INNER / KSPLIT);
    int kq = lane >> 4, rr = lane & 15;
    f32x4 acc[5];
    #pragma unroll
    for (int i = 0; i < 5; i++) acc[i] = (f32x4){0.f,0.f,0.f,0.f};
    const char* Ab = (const char*)A;
    const char* Wb = (const char*)W;
    char* AsB = (char*)As;
    char* BsB = (char*)Bs;

    for (int kk = k0; kk < k0 + D_INNER/KSPLIT; kk += 64) {
        #pragma unroll
        for (int cA = 0; cA < 2; cA++) {
            int idx = cA*256 + tid;
            int r = idx >> 3, q = (idx & 7) ^ (r & 7);
            __builtin_amdgcn_global_load_lds(
                (const __attribute__((address_space(1))) unsigned int*)(Ab + ((size_t)(m0+r)*D_INNER + kk + q*8)*2),
                (__attribute__((address_space(3))) unsigned int*)(AsB + idx*16), 16, 0, 0);
        }
        #pragma unroll
        for (int cB = 0; cB < 3; cB++) {
            int idx = cB*256 + tid;
            int r = idx >> 3, q = (idx & 7) ^ (r & 7);
            int rs = r < XN ? r : XN-1;
            __builtin_amdgcn_global_load_lds(
                (const __attribute__((address_space(1))) unsigned int*)(Wb + ((size_t)rs*D_INNER + kk + q*8)*2),
                (__attribute__((address_space(3))) unsigned int*)(BsB + idx*16), 16, 0, 0);
        }
        __syncthreads();
        #pragma unroll
        for (int kh = 0; kh < 2; kh++) {
            bf16x8 a = *(const bf16x8*)(AsB + (w*16 + rr)*128 + (((kh*4 + kq) ^ (rr & 7)))*16);
            #pragma unroll
            for (int ni = 0; ni < 5; ni++) {
                bf16x8 b = *(const bf16x8*)(BsB + (ni*16 + rr)*128 + (((kh*4 + kq) ^ (rr & 7)))*16);
                acc[ni] = __builtin_amdgcn_mfma_f32_16x16x32_bf16(a, b, acc[ni], 0, 0, 0);
            }
        }
        __syncthreads();
    }
    #pragma unroll
    for (int ni = 0; ni < 5; ni++)
        #pragma unroll
        for (int r = 0; r < 4; r++) {
            int row = m0 + w*16 + kq*4 + r;
            int col = ni*16 + rr;
            atomicAdd(&C[(size_t)row*XN + col], acc[ni][r]);
        }
}

// ---------------------------------------------------------------- depthwise causal conv + SiLU (+ bf16 copy)
__global__ __launch_bounds__(256) void dwconv_silu(const float* __restrict__ xs,
                                                   const float* __restrict__ cw,
                                                   const float* __restrict__ cb,
                                                   float* __restrict__ u,
                                                   __hip_bfloat16* __restrict__ u_bf) {
    int idx = blockIdx.x*256 + threadIdx.x;
    if (idx >= ROWS*D_INNER) return;
    int d = idx % D_INNER;
    int t = idx / D_INNER;
    int l = t & 511, b = t >> 9;
    float acc = cb[d];
    #pragma unroll
    for (int k = 0; k < K_CONV; k++) {
        int ll = l - (K_CONV-1) + k;
        if (ll >= 0) acc += xs[((size_t)(b*LSEQ + ll))*D_INNER + d] * cw[d*K_CONV + k];
    }
    float v = acc / (1.f + __expf(-acc));
    u[(size_t)t*D_INNER + d] = v;
    u_bf[(size_t)t*D_INNER + d] = __float2bfloat16(v);
}

// ---------------------------------------------------------------- selective scan, 3-phase chunked (NC=32, CL=16)
// B/C rows read directly from xdbl with wave-uniform addresses (scalar loads).
__global__ __launch_bounds__(256) void scan_p1(const float* __restrict__ u,
                                               const float* __restrict__ delta,
                                               const float* __restrict__ xdbl,
                                               const float* __restrict__ A_log,
                                               float* __restrict__ xfin,
                                               float* __restrict__ sumdlt) {
    int d = blockIdx.x*256 + threadIdx.x;
    int c = blockIdx.y, b = blockIdx.z;
    int l0 = c*CL;
    float A[N_STATE], xs[N_STATE];
    const float* al = A_log + d*N_STATE;
    #pragma unroll
    for (int n = 0; n < N_STATE; n++) {
        A[n] = -__expf(al[n]) * LOG2E;
        xs[n] = 0.f;
    }
    const float* pd = delta + (size_t)(b*LSEQ + l0)*D_INNER + d;
    const float* pu = u     + (size_t)(b*LSEQ + l0)*D_INNER + d;
    const float* pB = xdbl  + (size_t)(b*LSEQ + l0)*XN + DT_RANK;   // wave-uniform
    float sd = 0.f;
    for (int i = 0; i < CL; i++) {
        float dlt = *pd; pd += D_INNER;
        float uu  = *pu; pu += D_INNER;
        float du = dlt*uu;
        sd += dlt;
        #pragma unroll
        for (int n = 0; n < N_STATE; n++)
            xs[n] = exp2f(dlt*A[n])*xs[n] + du*pB[n];
        pB += XN;
    }
    size_t j = ((size_t)(b*NC + c)*D_INNER + d);
    #pragma unroll
    for (int n = 0; n < N_STATE; n += 4)
        *(float4*)&xfin[j*N_STATE + n] = (float4){xs[n],xs[n+1],xs[n+2],xs[n+3]};
    sumdlt[j] = sd;
}

// in-place: carry for chunk c is stored into xfin slot (c-1). chunk 0 carry == 0 (not stored).
__global__ __launch_bounds__(256) void scan_p2(float* __restrict__ xfin,
                                               const float* __restrict__ sumdlt,
                                               const float* __restrict__ A_log) {
    int idx = blockIdx.x*256 + threadIdx.x;
    int n = idx & 15;
    int rest = idx >> 4;
    int d = rest % D_INNER;
    int b = rest / D_INNER;
    float A2 = -__expf(A_log[d*N_STATE + n]) * LOG2E;
    float cr = 0.f;
    for (int c = 1; c < NC; c++) {
        size_t j = (size_t)(b*NC + c - 1)*D_INNER + d;
        float xf = xfin[j*N_STATE + n];
        cr = exp2f(A2 * sumdlt[j]) * cr + xf;
        xfin[j*N_STATE + n] = cr;
    }
}

__global__ __launch_bounds__(256) void scan_p3(const float* __restrict__ u,
                                               const float* __restrict__ delta,
                                               const float* __restrict__ xdbl,
                                               const float* __restrict__ A_log,
                                               const float* __restrict__ Dp,
                                               const float* __restrict__ carry,
                                               const float* __restrict__ res,
                                               __hip_bfloat16* __restrict__ ygate) {
    int d = blockIdx.x*256 + threadIdx.x;
    int c = blockIdx.y, b = blockIdx.z;
    int l0 = c*CL;
    float A[N_STATE], xs[N_STATE];
    const float* al = A_log + d*N_STATE;
    #pragma unroll
    for (int n = 0; n < N_STATE; n++) A[n] = -__expf(al[n]) * LOG2E;
    if (c == 0) {
        #pragma unroll
        for (int n = 0; n < N_STATE; n++) xs[n] = 0.f;
    } else {
        size_t jc = ((size_t)(b*NC + c - 1)*D_INNER + d)*N_STATE;
        #pragma unroll
        for (int n = 0; n < N_STATE; n++) xs[n] = carry[jc + n];
    }
    float Dv = Dp[d];
    const float* pd = delta + (size_t)(b*LSEQ + l0)*D_INNER + d;
    const float* pu = u     + (size_t)(b*LSEQ + l0)*D_INNER + d;
    const float* pr = res   + (size_t)(b*LSEQ + l0)*D_INNER + d;
    const float* pB = xdbl  + (size_t)(b*LSEQ + l0)*XN + DT_RANK;   // wave-uniform
    __hip_bfloat16* py = ygate + (size_t)(b*LSEQ + l0)*D_INNER + d;
    for (int i = 0; i < CL; i++) {
        float dlt = *pd; pd += D_INNER;
        float uu  = *pu; pu += D_INNER;
        float r   = *pr; pr += D_INNER;
        float du = dlt*uu;
        float acc = 0.f;
        #pragma unroll
        for (int n = 0; n < N_STATE; n++) {
            xs[n] = exp2f(dlt*A[n])*xs[n] + du*pB[n];
            acc += xs[n]*pB[N_STATE + n];
        }
        pB += XN;
        float y = acc + uu*Dv;
        float g = y * (r / (1.f + __expf(-r)));
        *py = __float2bfloat16(g); py += D_INNER;
    }
}

// ---------------------------------------------------------------- final norm + head + de-norm
__global__ __launch_bounds__(256) void final_kernel(const float* __restrict__ h,
                                                    const float* __restrict__ fnw,
                                                    const float* __restrict__ out_w,
                                                    const float* __restrict__ mean,
                                                    const float* __restrict__ stdv,
                                                    float* __restrict__ out) {
    int bid = blockIdx.x;
    int b = bid / PRED_LEN, lo = bid % PRED_LEN;
    int l = LSEQ - PRED_LEN + lo;
    const float* row = h + ((size_t)(b*LSEQ + l))*D_MODEL;
    __shared__ float tmp[4];
    float ss = 0.f;
    for (int k = threadIdx.x; k < D_MODEL; k += 256) { float v = row[k]; ss += v*v; }
    ss = block_sum(ss, tmp);
    float inv = rsqrtf(ss / (float)D_MODEL + EPSV);
    float acc[C_OUT] = {};
    for (int k = threadIdx.x; k < D_MODEL; k += 256) {
        float hn = row[k]*fnw[k];
        #pragma unroll
        for (int c = 0; c < C_OUT; c++) acc[c] += hn*out_w[c*D_MODEL + k];
    }
    #pragma unroll
    for (int c = 0; c < C_OUT; c++) {
        float s = block_sum(acc[c], tmp);
        if (threadIdx.x == 0)
            out[((size_t)(b*PRED_LEN + lo))*C_OUT + c] = s*inv*stdv[b*ENC_IN + c] + mean[b*ENC_IN + c];
    }
}

// ---------------------------------------------------------------- launch
extern "C" void kernel_launch(void* const* d_in, const int* in_sizes, int n_in,
                              void* d_out, int out_size, void* d_ws, size_t ws_size,
                              hipStream_t stream) {
    const float* x        = (const float*)d_in[0];
    const float* token_w  = (const float*)d_in[1];
    const float* time_w   = (const float*)d_in[2];
    const float* norm_w   = (const float*)d_in[3];
    const float* in_w     = (const float*)d_in[4];
    const float* conv_w   = (const float*)d_in[5];
    const float* conv_b   = (const float*)d_in[6];
    const float* xproj_w  = (const float*)d_in[7];
    const float* dtproj_w = (const float*)d_in[8];
    const float* dtproj_b = (const float*)d_in[9];
    const float* A_log    = (const float*)d_in[10];
    const float* Dp       = (const float*)d_in[11];
    const float* outproj_w= (const float*)d_in[12];
    const float* final_nw = (const float*)d_in[13];
    const float* out_w    = (const float*)d_in[14];
    float* out = (float*)d_out;

    float* ws   = (float*)d_ws;
    float* mean = ws;
    float* stdv = ws + 64;
    float* h    = ws + 128;
    float* xs   = h    + (size_t)ROWS*D_MODEL;       // ROWS*D_INNER (reused: xfin, in-place carry)
    float* res  = xs   + (size_t)ROWS*D_INNER;       // ROWS*D_INNER
    float* u    = res  + (size_t)ROWS*D_INNER;       // ROWS*D_INNER
    float* xdbl = u    + (size_t)ROWS*D_INNER;       // ROWS*80
    float* delta= xdbl + (size_t)ROWS*XN;            // ROWS*D_INNER
    float* sumd = delta+ (size_t)ROWS*D_INNER;       // BSZ*NC*D_INNER
    float* fend = sumd + (size_t)BSZ*NC*D_INNER;
    // alias into dead xs region (xs consumed by dwconv before scan_p1 runs)
    // BSZ*NC*D_INNER*N_STATE = 8*32*1536*16 = 6291456 == ROWS*D_INNER (exact fit)
    float* xfin = xs;
    __hip_bfloat16* xn_bf  = (__hip_bfloat16*)fend;
    __hip_bfloat16* ygate  = xn_bf + (size_t)ROWS*D_MODEL;
    __hip_bfloat16* inw_bf = ygate + (size_t)ROWS*D_INNER;
    __hip_bfloat16* outw_bf= inw_bf + (size_t)E_LAYERS*2*D_INNER*D_MODEL;
    __hip_bfloat16* xpw_bf = outw_bf+ (size_t)E_LAYERS*D_MODEL*D_INNER;
    __hip_bfloat16* u_bf   = xpw_bf + (size_t)E_LAYERS*XN*D_INNER;
    __hip_bfloat16* xdbl_bf= u_bf   + (size_t)ROWS*D_INNER;          // 4096 x 64
    __hip_bfloat16* dtw_bf = xdbl_bf+ (size_t)ROWS*64;               // E_LAYERS x 1536 x 64

    // convert weights to bf16 (once per call)
    {
        int n1 = E_LAYERS*2*D_INNER*D_MODEL;
        cvt_bf16<<<(n1+255)/256, 256, 0, stream>>>(in_w, inw_bf, n1);
        int n2 = E_LAYERS*D_MODEL*D_INNER;
        cvt_bf16<<<(n2+255)/256, 256, 0, stream>>>(outproj_w, outw_bf, n2);
        int n3 = E_LAYERS*XN*D_INNER;
        cvt_bf16<<<(n3+255)/256, 256, 0, stream>>>(xproj_w, xpw_bf, n3);
        pack_pad<<<(E_LAYERS*D_INNER*64+255)/256, 256, 0, stream>>>(
            dtproj_w, DT_RANK, DT_RANK, dtw_bf, 64, E_LAYERS*D_INNER);
    }

    stats_kernel<<<BSZ*ENC_IN, 256, 0, stream>>>(x, mean, stdv);
    embed_kernel<<<ROWS, 256, 0, stream>>>(x, token_w, time_w, mean, stdv, h);

    for (int e = 0; e < E_LAYERS; e++) {
        rmsnorm_bf16<<<ROWS, 256, 0, stream>>>(h, norm_w + e*D_MODEL, xn_bf);
        gemm_mfma<3><<<dim3(2*D_INNER/128, ROWS/128), 256, 0, stream>>>(
            xn_bf, inw_bf + (size_t)e*2*D_INNER*D_MODEL, xs, D_INNER, D_MODEL,
            nullptr, nullptr, 0, res);
        dwconv_silu<<<(ROWS*D_INNER + 255)/256, 256, 0, stream>>>(
            xs, conv_w + (size_t)e*D_INNER*K_CONV, conv_b + e*D_INNER, u, u_bf);
        hipMemsetAsync(xdbl, 0, (size_t)ROWS*XN*sizeof(float), stream);
        gemm_xproj<<<dim3(ROWS/64, KSPLIT), 256, 0, stream>>>(
            u_bf, xpw_bf + (size_t)e*XN*D_INNER, xdbl);
        pack_pad<<<(ROWS*64+255)/256, 256, 0, stream>>>(xdbl, XN, DT_RANK, xdbl_bf, 64, ROWS);
        gemm_mfma<1><<<dim3(D_INNER/128, ROWS/128), 256, 0, stream>>>(
            xdbl_bf, dtw_bf + (size_t)e*D_INNER*64, delta, D_INNER, 64,
            dtproj_b + e*D_INNER, nullptr, 0, nullptr);
        const float* Alog_e = A_log + (size_t)e*D_INNER*N_STATE;
        scan_p1<<<dim3(D_INNER/256, NC, BSZ), 256, 0, stream>>>(
            u, delta, xdbl, Alog_e, xfin, sumd);
        scan_p2<<<(BSZ*D_INNER*N_STATE)/256, 256, 0, stream>>>(
            xfin, sumd, Alog_e);
        scan_p3<<<dim3(D_INNER/256, NC, BSZ), 256, 0, stream>>>(
            u, delta, xdbl, Alog_e, Dp + (size_t)e*D_INNER, xfin, res, ygate);
        gemm_mfma<2><<<dim3(D_MODEL/128, ROWS/128), 256, 0, stream>>>(
            ygate, outw_bf + (size_t)e*D_MODEL*D_INNER, h, D_MODEL, D_INNER,
            nullptr, h, D_MODEL, nullptr);
    }

    final_kernel<<<BSZ*PRED_LEN, 256, 0, stream>>>(h, final_nw, out_w, mean, stdv, out);
}

// Round 6
// 471.004 us; speedup vs baseline: 1.1241x; 1.1076x over previous
//
#include <hip/hip_runtime.h>
#include <hip/hip_bf16.h>
#include <math.h>

// Problem constants
#define BSZ 8
#define LSEQ 512
#define ENC_IN 7
#define D_MODEL 768
#define D_INNER 1536
#define DT_RANK 48
#define N_STATE 16
#define K_CONV 4
#define E_LAYERS 2
#define C_OUT 7
#define PRED_LEN 96
#define EPSV 1e-5f
#define XN 80
#define KSPLIT 4

#define ROWS (BSZ*LSEQ)            // 4096
#define NC 16                      // scan chunks
#define CL (LSEQ/NC)               // 32 steps per chunk
#define NTILE (LSEQ/16)            // 32 16-step tiles per batch
#define LOG2E 1.44269504088896f

typedef __bf16 bf16x8 __attribute__((ext_vector_type(8)));
typedef float  f32x4  __attribute__((ext_vector_type(4)));

// raw hardware exp2 (single v_exp_f32)
__device__ __forceinline__ float fexp2(float x) {
    float r;
    asm("v_exp_f32 %0, %1" : "=v"(r) : "v"(x));
    return r;
}

// ---------------------------------------------------------------- utilities
__device__ __forceinline__ float block_sum(float v, float* tmp) {
    #pragma unroll
    for (int off = 32; off > 0; off >>= 1) v += __shfl_down(v, off);
    int lane = threadIdx.x & 63, wid = threadIdx.x >> 6;
    __syncthreads();
    if (lane == 0) tmp[wid] = v;
    __syncthreads();
    return tmp[0] + tmp[1] + tmp[2] + tmp[3];
}

// ---------------------------------------------------------------- f32 -> bf16 convert
__global__ __launch_bounds__(256) void cvt_bf16(const float* __restrict__ in,
                                                __hip_bfloat16* __restrict__ out, int n) {
    int i = blockIdx.x*256 + threadIdx.x;
    if (i < n) out[i] = __float2bfloat16(in[i]);
}

// pack src(rows x sld) cols[0:kvalid) into bf16 dst(rows x dld), zero-pad rest
__global__ __launch_bounds__(256) void pack_pad(const float* __restrict__ src, int sld, int kvalid,
                                                __hip_bfloat16* __restrict__ dst, int dld, int rows) {
    int i = blockIdx.x*256 + threadIdx.x;
    int r = i / dld, c = i % dld;
    if (r < rows)
        dst[i] = __float2bfloat16(c < kvalid ? src[(size_t)r*sld + c] : 0.f);
}

// ---------------------------------------------------------------- stats (RevIN)
__global__ __launch_bounds__(256) void stats_kernel(const float* __restrict__ x,
                                                    float* __restrict__ mean,
                                                    float* __restrict__ stdv) {
    int bc = blockIdx.x;
    int b = bc / ENC_IN, c = bc % ENC_IN;
    __shared__ float tmp[4];
    float s = 0.f, sq = 0.f;
    for (int l = threadIdx.x; l < LSEQ; l += 256) {
        float v = x[((size_t)(b*LSEQ + l))*ENC_IN + c];
        s += v; sq += v*v;
    }
    s = block_sum(s, tmp);
    sq = block_sum(sq, tmp);
    if (threadIdx.x == 0) {
        float m = s / LSEQ;
        float var = sq / LSEQ - m*m;
        if (var < 0.f) var = 0.f;
        mean[bc] = m;
        stdv[bc] = sqrtf(var + EPSV);
    }
}

// ---------------------------------------------------------------- embedding
__global__ __launch_bounds__(256) void embed_kernel(const float* __restrict__ x,
                                                    const float* __restrict__ token_w,
                                                    const float* __restrict__ time_w,
                                                    const float* __restrict__ mean,
                                                    const float* __restrict__ stdv,
                                                    float* __restrict__ h) {
    int bl = blockIdx.x;
    int b = bl >> 9, l = bl & 511;
    __shared__ float sxc[ENC_IN*3];
    if (threadIdx.x < ENC_IN*3) {
        int c = threadIdx.x / 3, k = threadIdx.x % 3;
        int lk = (l + k - 1) & 511;
        float v = x[((size_t)(b*LSEQ + lk))*ENC_IN + c];
        sxc[threadIdx.x] = (v - mean[b*ENC_IN + c]) / stdv[b*ENC_IN + c];
    }
    __syncthreads();
    #pragma unroll
    for (int i = 0; i < 3; i++) {
        int d = threadIdx.x + i*256;
        float acc = 0.f;
        const float* w = token_w + (size_t)d*21;
        #pragma unroll
        for (int t = 0; t < 21; t++) acc += sxc[t] * w[t];
        int d2 = d & ~1;
        float div = __expf((float)d2 * (-9.210340371976184f / (float)D_MODEL));
        float ang = (float)l * div;
        float pe = (d & 1) ? cosf(ang) : sinf(ang);
        float tm = ((float)l / (float)LSEQ) * time_w[d];
        h[(size_t)bl*D_MODEL + d] = acc + pe + tm;
    }
}

// ---------------------------------------------------------------- rmsnorm -> bf16
__global__ __launch_bounds__(256) void rmsnorm_bf16(const float* __restrict__ h,
                                                    const float* __restrict__ w,
                                                    __hip_bfloat16* __restrict__ xn) {
    size_t base = (size_t)blockIdx.x * D_MODEL;
    __shared__ float tmp[4];
    float ss = 0.f;
    for (int k = threadIdx.x; k < D_MODEL; k += 256) { float v = h[base+k]; ss += v*v; }
    ss = block_sum(ss, tmp);
    float inv = rsqrtf(ss / (float)D_MODEL + EPSV);
    for (int k = threadIdx.x; k < D_MODEL; k += 256)
        xn[base+k] = __float2bfloat16(h[base+k]*inv*w[k]);
}

// ---------------------------------------------------------------- bf16 MFMA GEMM (128x128 tile, BK=32)
// C(M x N) = A(M x K) @ Bw(N x K)^T.  XOR-swizzled LDS.
// FUSE 0: plain row-major
// FUSE 1: softplus(acc+bias[n]) -> BLOCKED [row/16][col][16] float4 stores
// FUSE 2: acc + res (row-major)
// FUSE 3: col < D_INNER -> C row-major compact; col >= D_INNER -> silu(acc) BLOCKED into C2
template<int FUSE>
__global__ __launch_bounds__(256) void gemm_mfma(const __hip_bfloat16* __restrict__ A,
                                                 const __hip_bfloat16* __restrict__ Bw,
                                                 float* __restrict__ C, int ldc,
                                                 int K,
                                                 const float* __restrict__ bias,
                                                 const float* __restrict__ res, int ldr,
                                                 float* __restrict__ C2) {
    __shared__ __align__(16) __hip_bfloat16 As[128*32];
    __shared__ __align__(16) __hip_bfloat16 Bs[128*32];
    int tid = threadIdx.x, lane = tid & 63, w = tid >> 6;
    int m0 = blockIdx.y * 128, n0 = blockIdx.x * 128;
    int wr = w >> 1, wc = w & 1;
    int kq = lane >> 4, rr = lane & 15;

    f32x4 acc[4][4];
    #pragma unroll
    for (int i = 0; i < 4; i++)
        #pragma unroll
        for (int j = 0; j < 4; j++) acc[i][j] = (f32x4){0.f,0.f,0.f,0.f};

    const char* Ab = (const char*)A;
    const char* Bb = (const char*)Bw;
    char* AsB = (char*)As;
    char* BsB = (char*)Bs;

    int c0 = tid, c1 = tid + 256;
    int r0 = c0 >> 2, q0 = (c0 & 3) ^ ((r0 >> 1) & 3);   // swizzled chunk
    int r1 = c1 >> 2, q1 = (c1 & 3) ^ ((r1 >> 1) & 3);
    int sw = (kq ^ ((rr >> 1) & 3)) * 16;                // swizzled read byte offset

    for (int k0 = 0; k0 < K; k0 += 32) {
        __builtin_amdgcn_global_load_lds(
            (const __attribute__((address_space(1))) unsigned int*)(Ab + ((size_t)(m0+r0)*K + k0 + q0*8)*2),
            (__attribute__((address_space(3))) unsigned int*)(AsB + c0*16), 16, 0, 0);
        __builtin_amdgcn_global_load_lds(
            (const __attribute__((address_space(1))) unsigned int*)(Ab + ((size_t)(m0+r1)*K + k0 + q1*8)*2),
            (__attribute__((address_space(3))) unsigned int*)(AsB + c1*16), 16, 0, 0);
        __builtin_amdgcn_global_load_lds(
            (const __attribute__((address_space(1))) unsigned int*)(Bb + ((size_t)(n0+r0)*K + k0 + q0*8)*2),
            (__attribute__((address_space(3))) unsigned int*)(BsB + c0*16), 16, 0, 0);
        __builtin_amdgcn_global_load_lds(
            (const __attribute__((address_space(1))) unsigned int*)(Bb + ((size_t)(n0+r1)*K + k0 + q1*8)*2),
            (__attribute__((address_space(3))) unsigned int*)(BsB + c1*16), 16, 0, 0);
        __syncthreads();

        bf16x8 af[4], bfr[4];
        #pragma unroll
        for (int mi = 0; mi < 4; mi++) af[mi]  = *(const bf16x8*)(AsB + (wr*64 + mi*16 + rr)*64 + sw);
        #pragma unroll
        for (int ni = 0; ni < 4; ni++) bfr[ni] = *(const bf16x8*)(BsB + (wc*64 + ni*16 + rr)*64 + sw);
        #pragma unroll
        for (int mi = 0; mi < 4; mi++)
            #pragma unroll
            for (int ni = 0; ni < 4; ni++)
                acc[mi][ni] = __builtin_amdgcn_mfma_f32_16x16x32_bf16(af[mi], bfr[ni], acc[mi][ni], 0, 0, 0);
        __syncthreads();
    }

    #pragma unroll
    for (int mi = 0; mi < 4; mi++) {
        #pragma unroll
        for (int ni = 0; ni < 4; ni++) {
            int row0 = m0 + wr*64 + mi*16;              // tile-aligned base
            int col  = n0 + wc*64 + ni*16 + rr;
            if (FUSE == 1) {
                float4 v4;
                #pragma unroll
                for (int r = 0; r < 4; r++) {
                    float v = acc[mi][ni][r] + bias[col];
                    ((float*)&v4)[r] = fmaxf(v, 0.f) + log1pf(__expf(-fabsf(v)));
                }
                *(float4*)&C[((size_t)(row0 >> 4)*D_INNER + col)*16 + kq*4] = v4;
            } else if (FUSE == 3 && col >= D_INNER) {
                float4 v4;
                #pragma unroll
                for (int r = 0; r < 4; r++) {
                    float v = acc[mi][ni][r];
                    ((float*)&v4)[r] = v / (1.f + __expf(-v));   // silu
                }
                *(float4*)&C2[((size_t)(row0 >> 4)*D_INNER + (col - D_INNER))*16 + kq*4] = v4;
            } else {
                #pragma unroll
                for (int r = 0; r < 4; r++) {
                    int row = row0 + kq*4 + r;
                    float v = acc[mi][ni][r];
                    if (FUSE == 2) v += res[(size_t)row*ldr + col];
                    if (FUSE == 3) C[(size_t)row*D_INNER + col] = v;
                    else           C[(size_t)row*ldc + col] = v;
                }
            }
        }
    }
}

// ---------------------------------------------------------------- xproj MFMA: C(4096 x 80) += A @ W^T, split-K
__global__ __launch_bounds__(256) void gemm_xproj(const __hip_bfloat16* __restrict__ A,
                                                  const __hip_bfloat16* __restrict__ W,
                                                  float* __restrict__ C) {
    __shared__ __align__(16) __hip_bfloat16 As[64*64];
    __shared__ __align__(16) __hip_bfloat16 Bs[96*64];
    int tid = threadIdx.x, lane = tid & 63, w = tid >> 6;
    int m0 = blockIdx.x * 64;
    int k0 = blockIdx.y * (D_INNER / KSPLIT);
    int kq = lane >> 4, rr = lane & 15;
    f32x4 acc[5];
    #pragma unroll
    for (int i = 0; i < 5; i++) acc[i] = (f32x4){0.f,0.f,0.f,0.f};
    const char* Ab = (const char*)A;
    const char* Wb = (const char*)W;
    char* AsB = (char*)As;
    char* BsB = (char*)Bs;

    for (int kk = k0; kk < k0 + D_INNER/KSPLIT; kk += 64) {
        #pragma unroll
        for (int cA = 0; cA < 2; cA++) {
            int idx = cA*256 + tid;
            int r = idx >> 3, q = (idx & 7) ^ (r & 7);
            __builtin_amdgcn_global_load_lds(
                (const __attribute__((address_space(1))) unsigned int*)(Ab + ((size_t)(m0+r)*D_INNER + kk + q*8)*2),
                (__attribute__((address_space(3))) unsigned int*)(AsB + idx*16), 16, 0, 0);
        }
        #pragma unroll
        for (int cB = 0; cB < 3; cB++) {
            int idx = cB*256 + tid;
            int r = idx >> 3, q = (idx & 7) ^ (r & 7);
            int rs = r < XN ? r : XN-1;
            __builtin_amdgcn_global_load_lds(
                (const __attribute__((address_space(1))) unsigned int*)(Wb + ((size_t)rs*D_INNER + kk + q*8)*2),
                (__attribute__((address_space(3))) unsigned int*)(BsB + idx*16), 16, 0, 0);
        }
        __syncthreads();
        #pragma unroll
        for (int kh = 0; kh < 2; kh++) {
            bf16x8 a = *(const bf16x8*)(AsB + (w*16 + rr)*128 + (((kh*4 + kq) ^ (rr & 7)))*16);
            #pragma unroll
            for (int ni = 0; ni < 5; ni++) {
                bf16x8 b = *(const bf16x8*)(BsB + (ni*16 + rr)*128 + (((kh*4 + kq) ^ (rr & 7)))*16);
                acc[ni] = __builtin_amdgcn_mfma_f32_16x16x32_bf16(a, b, acc[ni], 0, 0, 0);
            }
        }
        __syncthreads();
    }
    #pragma unroll
    for (int ni = 0; ni < 5; ni++)
        #pragma unroll
        for (int r = 0; r < 4; r++) {
            int row = m0 + w*16 + kq*4 + r;
            int col = ni*16 + rr;
            atomicAdd(&C[(size_t)row*XN + col], acc[ni][r]);
        }
}

// ---------------------------------------------------------------- depthwise causal conv + SiLU (+ bf16 copy)
__global__ __launch_bounds__(256) void dwconv_silu(const float* __restrict__ xs,
                                                   const float* __restrict__ cw,
                                                   const float* __restrict__ cb,
                                                   float* __restrict__ u,
                                                   __hip_bfloat16* __restrict__ u_bf) {
    int idx = blockIdx.x*256 + threadIdx.x;
    if (idx >= ROWS*D_INNER) return;
    int d = idx % D_INNER;
    int t = idx / D_INNER;
    int l = t & 511, b = t >> 9;
    float acc = cb[d];
    #pragma unroll
    for (int k = 0; k < K_CONV; k++) {
        int ll = l - (K_CONV-1) + k;
        if (ll >= 0) acc += xs[((size_t)(b*LSEQ + ll))*D_INNER + d] * cw[d*K_CONV + k];
    }
    float v = acc / (1.f + __expf(-acc));
    u[(size_t)t*D_INNER + d] = v;
    u_bf[(size_t)t*D_INNER + d] = __float2bfloat16(v);
}

// ---------------------------------------------------------------- selective scan, 3-phase chunked (NC=16, CL=32)
// delta_blk, gres_blk: blocked [b][t/16][d][16] f32.  u: row-major.
// xfin: [b][c][n][d] (transposed, coalesced).  B/C: wave-uniform from xdbl.
__global__ __launch_bounds__(256) void scan_p1(const float* __restrict__ u,
                                               const float* __restrict__ delta_blk,
                                               const float* __restrict__ xdbl,
                                               const float* __restrict__ A_log,
                                               float* __restrict__ xfin,
                                               float* __restrict__ sumdlt) {
    int d = blockIdx.x*256 + threadIdx.x;
    int c = blockIdx.y, b = blockIdx.z;
    int l0 = c*CL;
    float A2[N_STATE], xs[N_STATE];
    const float* al = A_log + d*N_STATE;
    #pragma unroll
    for (int n = 0; n < N_STATE; n++) {
        A2[n] = -__expf(al[n]) * LOG2E;
        xs[n] = 0.f;
    }
    const float* pu = u + (size_t)(b*LSEQ + l0)*D_INNER + d;
    const float* pB = xdbl + (size_t)(b*LSEQ + l0)*XN + DT_RANK;   // wave-uniform
    float sd = 0.f;
    #pragma unroll
    for (int tt = 0; tt < 2; tt++) {
        const float* db = delta_blk + ((size_t)(b*NTILE + (l0>>4) + tt)*D_INNER + d)*16;
        float dl[16];
        #pragma unroll
        for (int q = 0; q < 4; q++) {
            f32x4 v = *(const f32x4*)(db + q*4);
            dl[q*4+0]=v[0]; dl[q*4+1]=v[1]; dl[q*4+2]=v[2]; dl[q*4+3]=v[3];
        }
        #pragma unroll
        for (int i = 0; i < 16; i++) {
            float dlt = dl[i];
            float uu = *pu; pu += D_INNER;
            float du = dlt*uu;
            sd += dlt;
            #pragma unroll
            for (int n = 0; n < N_STATE; n++)
                xs[n] = fexp2(dlt*A2[n])*xs[n] + du*pB[n];
            pB += XN;
        }
    }
    float* px = xfin + (size_t)((b*NC + c)*N_STATE)*D_INNER + d;
    #pragma unroll
    for (int n = 0; n < N_STATE; n++) px[n*D_INNER] = xs[n];
    sumdlt[(size_t)(b*NC + c)*D_INNER + d] = sd;
}

// in-place: carry for chunk c stored into xfin slot (c-1). chunk 0 carry == 0.
__global__ __launch_bounds__(256) void scan_p2(float* __restrict__ xfin,
                                               const float* __restrict__ sumdlt,
                                               const float* __restrict__ A_log) {
    int idx = blockIdx.x*256 + threadIdx.x;
    int d = idx % D_INNER;
    int r = idx / D_INNER;
    int n = r & 15;
    int b = r >> 4;
    float A2 = -__expf(A_log[d*N_STATE + n]) * LOG2E;
    float cr = 0.f;
    for (int c = 1; c < NC; c++) {
        size_t jp = (size_t)(b*NC + c - 1);
        float xf = xfin[(jp*N_STATE + n)*D_INNER + d];
        float s  = sumdlt[jp*D_INNER + d];
        cr = fexp2(A2 * s) * cr + xf;
        xfin[(jp*N_STATE + n)*D_INNER + d] = cr;
    }
}

__global__ __launch_bounds__(256) void scan_p3(const float* __restrict__ u,
                                               const float* __restrict__ delta_blk,
                                               const float* __restrict__ gres_blk,
                                               const float* __restrict__ xdbl,
                                               const float* __restrict__ A_log,
                                               const float* __restrict__ Dp,
                                               const float* __restrict__ carry,
                                               __hip_bfloat16* __restrict__ ygate) {
    int d = blockIdx.x*256 + threadIdx.x;
    int c = blockIdx.y, b = blockIdx.z;
    int l0 = c*CL;
    float A2[N_STATE], xs[N_STATE];
    const float* al = A_log + d*N_STATE;
    #pragma unroll
    for (int n = 0; n < N_STATE; n++) A2[n] = -__expf(al[n]) * LOG2E;
    if (c == 0) {
        #pragma unroll
        for (int n = 0; n < N_STATE; n++) xs[n] = 0.f;
    } else {
        const float* pc = carry + (size_t)((b*NC + c - 1)*N_STATE)*D_INNER + d;
        #pragma unroll
        for (int n = 0; n < N_STATE; n++) xs[n] = pc[n*D_INNER];
    }
    float Dv = Dp[d];
    const float* pu = u + (size_t)(b*LSEQ + l0)*D_INNER + d;
    const float* pB = xdbl + (size_t)(b*LSEQ + l0)*XN + DT_RANK;   // wave-uniform
    __hip_bfloat16* py = ygate + (size_t)(b*LSEQ + l0)*D_INNER + d;
    #pragma unroll
    for (int tt = 0; tt < 2; tt++) {
        size_t tb = (size_t)(b*NTILE + (l0>>4) + tt)*D_INNER + d;
        const float* db = delta_blk + tb*16;
        const float* gb = gres_blk  + tb*16;
        float dl[16], gr[16];
        #pragma unroll
        for (int q = 0; q < 4; q++) {
            f32x4 v = *(const f32x4*)(db + q*4);
            dl[q*4+0]=v[0]; dl[q*4+1]=v[1]; dl[q*4+2]=v[2]; dl[q*4+3]=v[3];
            f32x4 g = *(const f32x4*)(gb + q*4);
            gr[q*4+0]=g[0]; gr[q*4+1]=g[1]; gr[q*4+2]=g[2]; gr[q*4+3]=g[3];
        }
        #pragma unroll
        for (int i = 0; i < 16; i++) {
            float dlt = dl[i];
            float uu = *pu; pu += D_INNER;
            float du = dlt*uu;
            float acc = 0.f;
            #pragma unroll
            for (int n = 0; n < N_STATE; n++) {
                xs[n] = fexp2(dlt*A2[n])*xs[n] + du*pB[n];
                acc += xs[n]*pB[N_STATE + n];
            }
            pB += XN;
            float y = acc + uu*Dv;
            *py = __float2bfloat16(y * gr[i]); py += D_INNER;
        }
    }
}

// ---------------------------------------------------------------- final norm + head + de-norm
__global__ __launch_bounds__(256) void final_kernel(const float* __restrict__ h,
                                                    const float* __restrict__ fnw,
                                                    const float* __restrict__ out_w,
                                                    const float* __restrict__ mean,
                                                    const float* __restrict__ stdv,
                                                    float* __restrict__ out) {
    int bid = blockIdx.x;
    int b = bid / PRED_LEN, lo = bid % PRED_LEN;
    int l = LSEQ - PRED_LEN + lo;
    const float* row = h + ((size_t)(b*LSEQ + l))*D_MODEL;
    __shared__ float tmp[4];
    float ss = 0.f;
    for (int k = threadIdx.x; k < D_MODEL; k += 256) { float v = row[k]; ss += v*v; }
    ss = block_sum(ss, tmp);
    float inv = rsqrtf(ss / (float)D_MODEL + EPSV);
    float acc[C_OUT] = {};
    for (int k = threadIdx.x; k < D_MODEL; k += 256) {
        float hn = row[k]*fnw[k];
        #pragma unroll
        for (int c = 0; c < C_OUT; c++) acc[c] += hn*out_w[c*D_MODEL + k];
    }
    #pragma unroll
    for (int c = 0; c < C_OUT; c++) {
        float s = block_sum(acc[c], tmp);
        if (threadIdx.x == 0)
            out[((size_t)(b*PRED_LEN + lo))*C_OUT + c] = s*inv*stdv[b*ENC_IN + c] + mean[b*ENC_IN + c];
    }
}

// ---------------------------------------------------------------- launch
extern "C" void kernel_launch(void* const* d_in, const int* in_sizes, int n_in,
                              void* d_out, int out_size, void* d_ws, size_t ws_size,
                              hipStream_t stream) {
    const float* x        = (const float*)d_in[0];
    const float* token_w  = (const float*)d_in[1];
    const float* time_w   = (const float*)d_in[2];
    const float* norm_w   = (const float*)d_in[3];
    const float* in_w     = (const float*)d_in[4];
    const float* conv_w   = (const float*)d_in[5];
    const float* conv_b   = (const float*)d_in[6];
    const float* xproj_w  = (const float*)d_in[7];
    const float* dtproj_w = (const float*)d_in[8];
    const float* dtproj_b = (const float*)d_in[9];
    const float* A_log    = (const float*)d_in[10];
    const float* Dp       = (const float*)d_in[11];
    const float* outproj_w= (const float*)d_in[12];
    const float* final_nw = (const float*)d_in[13];
    const float* out_w    = (const float*)d_in[14];
    float* out = (float*)d_out;

    float* ws   = (float*)d_ws;
    float* mean = ws;
    float* stdv = ws + 64;
    float* h    = ws + 128;
    float* xs   = h    + (size_t)ROWS*D_MODEL;       // ROWS*D_INNER (reused: xfin in-place)
    float* gres = xs   + (size_t)ROWS*D_INNER;       // blocked silu(res)
    float* u    = gres + (size_t)ROWS*D_INNER;       // row-major
    float* xdbl = u    + (size_t)ROWS*D_INNER;       // ROWS*80
    float* delta= xdbl + (size_t)ROWS*XN;            // blocked
    float* sumd = delta+ (size_t)ROWS*D_INNER;       // BSZ*NC*D_INNER
    float* fend = sumd + (size_t)BSZ*32*D_INNER;
    // alias into dead xs region (xs consumed by dwconv before scan_p1 runs)
    // BSZ*NC*D_INNER*N_STATE = 8*16*1536*16 = 3.15M <= ROWS*D_INNER = 6.29M
    float* xfin = xs;
    __hip_bfloat16* xn_bf  = (__hip_bfloat16*)fend;
    __hip_bfloat16* ygate  = xn_bf + (size_t)ROWS*D_MODEL;
    __hip_bfloat16* inw_bf = ygate + (size_t)ROWS*D_INNER;
    __hip_bfloat16* outw_bf= inw_bf + (size_t)E_LAYERS*2*D_INNER*D_MODEL;
    __hip_bfloat16* xpw_bf = outw_bf+ (size_t)E_LAYERS*D_MODEL*D_INNER;
    __hip_bfloat16* u_bf   = xpw_bf + (size_t)E_LAYERS*XN*D_INNER;
    __hip_bfloat16* xdbl_bf= u_bf   + (size_t)ROWS*D_INNER;          // 4096 x 64
    __hip_bfloat16* dtw_bf = xdbl_bf+ (size_t)ROWS*64;               // E_LAYERS x 1536 x 64

    // convert weights to bf16 (once per call)
    {
        int n1 = E_LAYERS*2*D_INNER*D_MODEL;
        cvt_bf16<<<(n1+255)/256, 256, 0, stream>>>(in_w, inw_bf, n1);
        int n2 = E_LAYERS*D_MODEL*D_INNER;
        cvt_bf16<<<(n2+255)/256, 256, 0, stream>>>(outproj_w, outw_bf, n2);
        int n3 = E_LAYERS*XN*D_INNER;
        cvt_bf16<<<(n3+255)/256, 256, 0, stream>>>(xproj_w, xpw_bf, n3);
        pack_pad<<<(E_LAYERS*D_INNER*64+255)/256, 256, 0, stream>>>(
            dtproj_w, DT_RANK, DT_RANK, dtw_bf, 64, E_LAYERS*D_INNER);
    }

    stats_kernel<<<BSZ*ENC_IN, 256, 0, stream>>>(x, mean, stdv);
    embed_kernel<<<ROWS, 256, 0, stream>>>(x, token_w, time_w, mean, stdv, h);

    for (int e = 0; e < E_LAYERS; e++) {
        rmsnorm_bf16<<<ROWS, 256, 0, stream>>>(h, norm_w + e*D_MODEL, xn_bf);
        gemm_mfma<3><<<dim3(2*D_INNER/128, ROWS/128), 256, 0, stream>>>(
            xn_bf, inw_bf + (size_t)e*2*D_INNER*D_MODEL, xs, D_INNER, D_MODEL,
            nullptr, nullptr, 0, gres);
        dwconv_silu<<<(ROWS*D_INNER + 255)/256, 256, 0, stream>>>(
            xs, conv_w + (size_t)e*D_INNER*K_CONV, conv_b + e*D_INNER, u, u_bf);
        hipMemsetAsync(xdbl, 0, (size_t)ROWS*XN*sizeof(float), stream);
        gemm_xproj<<<dim3(ROWS/64, KSPLIT), 256, 0, stream>>>(
            u_bf, xpw_bf + (size_t)e*XN*D_INNER, xdbl);
        pack_pad<<<(ROWS*64+255)/256, 256, 0, stream>>>(xdbl, XN, DT_RANK, xdbl_bf, 64, ROWS);
        gemm_mfma<1><<<dim3(D_INNER/128, ROWS/128), 256, 0, stream>>>(
            xdbl_bf, dtw_bf + (size_t)e*D_INNER*64, delta, D_INNER, 64,
            dtproj_b + e*D_INNER, nullptr, 0, nullptr);
        const float* Alog_e = A_log + (size_t)e*D_INNER*N_STATE;
        scan_p1<<<dim3(D_INNER/256, NC, BSZ), 256, 0, stream>>>(
            u, delta, xdbl, Alog_e, xfin, sumd);
        scan_p2<<<(BSZ*D_INNER*N_STATE)/256, 256, 0, stream>>>(
            xfin, sumd, Alog_e);
        scan_p3<<<dim3(D_INNER/256, NC, BSZ), 256, 0, stream>>>(
            u, delta, gres, xdbl, Alog_e, Dp + (size_t)e*D_INNER, xfin, ygate);
        gemm_mfma<2><<<dim3(D_MODEL/128, ROWS/128), 256, 0, stream>>>(
            ygate, outw_bf + (size_t)e*D_MODEL*D_INNER, h, D_MODEL, D_INNER,
            nullptr, h, D_MODEL, nullptr);
    }

    final_kernel<<<BSZ*PRED_LEN, 256, 0, stream>>>(h, final_nw, out_w, mean, stdv, out);
}

// Round 7
// 400.225 us; speedup vs baseline: 1.3229x; 1.1769x over previous
//
#include <hip/hip_runtime.h>
#include <hip/hip_bf16.h>
#include <math.h>

// Problem constants
#define BSZ 8
#define LSEQ 512
#define ENC_IN 7
#define D_MODEL 768
#define D_INNER 1536
#define DT_RANK 48
#define N_STATE 16
#define K_CONV 4
#define E_LAYERS 2
#define C_OUT 7
#define PRED_LEN 96
#define EPSV 1e-5f
#define XN 80
#define KSPLIT 4

#define ROWS (BSZ*LSEQ)            // 4096
#define NC 16                      // scan chunks
#define CL (LSEQ/NC)               // 32 steps per chunk
#define NTILE (LSEQ/16)            // 32 16-step tiles per batch
#define LOG2E 1.44269504088896f

typedef __bf16 bf16x8 __attribute__((ext_vector_type(8)));
typedef float  f32x4  __attribute__((ext_vector_type(4)));

// raw hardware exp2 (single v_exp_f32)
__device__ __forceinline__ float fexp2(float x) {
    float r;
    asm("v_exp_f32 %0, %1" : "=v"(r) : "v"(x));
    return r;
}

// ---------------------------------------------------------------- utilities
__device__ __forceinline__ float block_sum(float v, float* tmp) {
    #pragma unroll
    for (int off = 32; off > 0; off >>= 1) v += __shfl_down(v, off);
    int lane = threadIdx.x & 63, wid = threadIdx.x >> 6;
    __syncthreads();
    if (lane == 0) tmp[wid] = v;
    __syncthreads();
    return tmp[0] + tmp[1] + tmp[2] + tmp[3];
}

// ---------------------------------------------------------------- fused weight conversion (one launch)
__global__ __launch_bounds__(256) void cvt_all(const float* __restrict__ in_w,
                                               const float* __restrict__ outw,
                                               const float* __restrict__ xpw,
                                               const float* __restrict__ dtw,
                                               __hip_bfloat16* __restrict__ inw_bf,
                                               __hip_bfloat16* __restrict__ outw_bf,
                                               __hip_bfloat16* __restrict__ xpw_bf,
                                               __hip_bfloat16* __restrict__ dtw_bf) {
    const int N1 = E_LAYERS*2*D_INNER*D_MODEL;
    const int N2 = E_LAYERS*D_MODEL*D_INNER;
    const int N3 = E_LAYERS*XN*D_INNER;
    const int N4 = E_LAYERS*D_INNER*64;
    int i = blockIdx.x*256 + threadIdx.x;
    if (i < N1) {
        inw_bf[i] = __float2bfloat16(in_w[i]);
    } else if (i < N1+N2) {
        int j = i - N1; outw_bf[j] = __float2bfloat16(outw[j]);
    } else if (i < N1+N2+N3) {
        int j = i - N1 - N2; xpw_bf[j] = __float2bfloat16(xpw[j]);
    } else if (i < N1+N2+N3+N4) {
        int j = i - N1 - N2 - N3;
        int r = j >> 6, c = j & 63;
        dtw_bf[j] = __float2bfloat16(c < DT_RANK ? dtw[r*DT_RANK + c] : 0.f);
    }
}

// ---------------------------------------------------------------- stats (RevIN)
__global__ __launch_bounds__(256) void stats_kernel(const float* __restrict__ x,
                                                    float* __restrict__ mean,
                                                    float* __restrict__ stdv) {
    int bc = blockIdx.x;
    int b = bc / ENC_IN, c = bc % ENC_IN;
    __shared__ float tmp[4];
    float s = 0.f, sq = 0.f;
    for (int l = threadIdx.x; l < LSEQ; l += 256) {
        float v = x[((size_t)(b*LSEQ + l))*ENC_IN + c];
        s += v; sq += v*v;
    }
    s = block_sum(s, tmp);
    sq = block_sum(sq, tmp);
    if (threadIdx.x == 0) {
        float m = s / LSEQ;
        float var = sq / LSEQ - m*m;
        if (var < 0.f) var = 0.f;
        mean[bc] = m;
        stdv[bc] = sqrtf(var + EPSV);
    }
}

// ---------------------------------------------------------------- embedding
__global__ __launch_bounds__(256) void embed_kernel(const float* __restrict__ x,
                                                    const float* __restrict__ token_w,
                                                    const float* __restrict__ time_w,
                                                    const float* __restrict__ mean,
                                                    const float* __restrict__ stdv,
                                                    float* __restrict__ h) {
    int bl = blockIdx.x;
    int b = bl >> 9, l = bl & 511;
    __shared__ float sxc[ENC_IN*3];
    if (threadIdx.x < ENC_IN*3) {
        int c = threadIdx.x / 3, k = threadIdx.x % 3;
        int lk = (l + k - 1) & 511;
        float v = x[((size_t)(b*LSEQ + lk))*ENC_IN + c];
        sxc[threadIdx.x] = (v - mean[b*ENC_IN + c]) / stdv[b*ENC_IN + c];
    }
    __syncthreads();
    #pragma unroll
    for (int i = 0; i < 3; i++) {
        int d = threadIdx.x + i*256;
        float acc = 0.f;
        const float* w = token_w + (size_t)d*21;
        #pragma unroll
        for (int t = 0; t < 21; t++) acc += sxc[t] * w[t];
        int d2 = d & ~1;
        float div = __expf((float)d2 * (-9.210340371976184f / (float)D_MODEL));
        float ang = (float)l * div;
        float pe = (d & 1) ? cosf(ang) : sinf(ang);
        float tm = ((float)l / (float)LSEQ) * time_w[d];
        h[(size_t)bl*D_MODEL + d] = acc + pe + tm;
    }
}

// ---------------------------------------------------------------- rmsnorm -> bf16
__global__ __launch_bounds__(256) void rmsnorm_bf16(const float* __restrict__ h,
                                                    const float* __restrict__ w,
                                                    __hip_bfloat16* __restrict__ xn) {
    size_t base = (size_t)blockIdx.x * D_MODEL;
    __shared__ float tmp[4];
    float ss = 0.f;
    for (int k = threadIdx.x; k < D_MODEL; k += 256) { float v = h[base+k]; ss += v*v; }
    ss = block_sum(ss, tmp);
    float inv = rsqrtf(ss / (float)D_MODEL + EPSV);
    for (int k = threadIdx.x; k < D_MODEL; k += 256)
        xn[base+k] = __float2bfloat16(h[base+k]*inv*w[k]);
}

// ---------------------------------------------------------------- bf16 MFMA GEMM (128x128 tile, BK=32)
// C(M x N) = A(M x K) @ Bw(N x K)^T.  XOR-swizzled LDS, XCD-swizzled blocks.
// FUSE 1: softplus(acc+bias[n]) -> BLOCKED [row/16][col][16] float4 into C
// FUSE 3: col < D_INNER -> bf16 row-major Cb; col >= D_INNER -> silu(acc) BLOCKED f32 into C2
template<int FUSE>
__global__ __launch_bounds__(256) void gemm_mfma(const __hip_bfloat16* __restrict__ A,
                                                 const __hip_bfloat16* __restrict__ Bw,
                                                 float* __restrict__ C,
                                                 int K,
                                                 const float* __restrict__ bias,
                                                 float* __restrict__ C2,
                                                 __hip_bfloat16* __restrict__ Cb) {
    __shared__ __align__(16) __hip_bfloat16 As[128*32];
    __shared__ __align__(16) __hip_bfloat16 Bs[128*32];
    int tid = threadIdx.x, lane = tid & 63, w = tid >> 6;
    // XCD-aware bijective swizzle (grids here always have nwg % 8 == 0)
    int gx = gridDim.x;
    int nwg = gx * gridDim.y;
    int orig = blockIdx.y*gx + blockIdx.x;
    int swz = (orig & 7)*(nwg >> 3) + (orig >> 3);
    int m0 = (swz / gx) * 128, n0 = (swz % gx) * 128;
    int wr = w >> 1, wc = w & 1;
    int kq = lane >> 4, rr = lane & 15;

    f32x4 acc[4][4];
    #pragma unroll
    for (int i = 0; i < 4; i++)
        #pragma unroll
        for (int j = 0; j < 4; j++) acc[i][j] = (f32x4){0.f,0.f,0.f,0.f};

    const char* Ab = (const char*)A;
    const char* Bb = (const char*)Bw;
    char* AsB = (char*)As;
    char* BsB = (char*)Bs;

    int c0 = tid, c1 = tid + 256;
    int r0 = c0 >> 2, q0 = (c0 & 3) ^ ((r0 >> 1) & 3);   // swizzled chunk
    int r1 = c1 >> 2, q1 = (c1 & 3) ^ ((r1 >> 1) & 3);
    int sw = (kq ^ ((rr >> 1) & 3)) * 16;                // swizzled read byte offset

    for (int k0 = 0; k0 < K; k0 += 32) {
        __builtin_amdgcn_global_load_lds(
            (const __attribute__((address_space(1))) unsigned int*)(Ab + ((size_t)(m0+r0)*K + k0 + q0*8)*2),
            (__attribute__((address_space(3))) unsigned int*)(AsB + c0*16), 16, 0, 0);
        __builtin_amdgcn_global_load_lds(
            (const __attribute__((address_space(1))) unsigned int*)(Ab + ((size_t)(m0+r1)*K + k0 + q1*8)*2),
            (__attribute__((address_space(3))) unsigned int*)(AsB + c1*16), 16, 0, 0);
        __builtin_amdgcn_global_load_lds(
            (const __attribute__((address_space(1))) unsigned int*)(Bb + ((size_t)(n0+r0)*K + k0 + q0*8)*2),
            (__attribute__((address_space(3))) unsigned int*)(BsB + c0*16), 16, 0, 0);
        __builtin_amdgcn_global_load_lds(
            (const __attribute__((address_space(1))) unsigned int*)(Bb + ((size_t)(n0+r1)*K + k0 + q1*8)*2),
            (__attribute__((address_space(3))) unsigned int*)(BsB + c1*16), 16, 0, 0);
        __syncthreads();

        bf16x8 af[4], bfr[4];
        #pragma unroll
        for (int mi = 0; mi < 4; mi++) af[mi]  = *(const bf16x8*)(AsB + (wr*64 + mi*16 + rr)*64 + sw);
        #pragma unroll
        for (int ni = 0; ni < 4; ni++) bfr[ni] = *(const bf16x8*)(BsB + (wc*64 + ni*16 + rr)*64 + sw);
        #pragma unroll
        for (int mi = 0; mi < 4; mi++)
            #pragma unroll
            for (int ni = 0; ni < 4; ni++)
                acc[mi][ni] = __builtin_amdgcn_mfma_f32_16x16x32_bf16(af[mi], bfr[ni], acc[mi][ni], 0, 0, 0);
        __syncthreads();
    }

    #pragma unroll
    for (int mi = 0; mi < 4; mi++) {
        #pragma unroll
        for (int ni = 0; ni < 4; ni++) {
            int row0 = m0 + wr*64 + mi*16;              // tile-aligned base
            int col  = n0 + wc*64 + ni*16 + rr;
            if (FUSE == 1) {
                float4 v4;
                #pragma unroll
                for (int r = 0; r < 4; r++) {
                    float v = acc[mi][ni][r] + bias[col];
                    ((float*)&v4)[r] = fmaxf(v, 0.f) + log1pf(__expf(-fabsf(v)));
                }
                *(float4*)&C[((size_t)(row0 >> 4)*D_INNER + col)*16 + kq*4] = v4;
            } else if (FUSE == 3) {
                if (col >= D_INNER) {
                    float4 v4;
                    #pragma unroll
                    for (int r = 0; r < 4; r++) {
                        float v = acc[mi][ni][r];
                        ((float*)&v4)[r] = v / (1.f + __expf(-v));   // silu
                    }
                    *(float4*)&C2[((size_t)(row0 >> 4)*D_INNER + (col - D_INNER))*16 + kq*4] = v4;
                } else {
                    #pragma unroll
                    for (int r = 0; r < 4; r++) {
                        int row = row0 + kq*4 + r;
                        Cb[(size_t)row*D_INNER + col] = __float2bfloat16(acc[mi][ni][r]);
                    }
                }
            }
        }
    }
}

// ---------------------------------------------------------------- out_proj: h(4096x768) += ygate @ W^T
// BM=128, BN=64 -> grid (12,32)=384 blocks for occupancy. XCD swizzle.
__global__ __launch_bounds__(256) void gemm_outproj(const __hip_bfloat16* __restrict__ A,
                                                    const __hip_bfloat16* __restrict__ Bw,
                                                    float* __restrict__ C) {
    __shared__ __align__(16) __hip_bfloat16 As[128*32];
    __shared__ __align__(16) __hip_bfloat16 Bs[64*32];
    int tid = threadIdx.x, lane = tid & 63, w = tid >> 6;
    int gx = gridDim.x;                       // 12
    int nwg = gx * gridDim.y;                 // 384
    int orig = blockIdx.y*gx + blockIdx.x;
    int swz = (orig & 7)*(nwg >> 3) + (orig >> 3);
    int m0 = (swz / gx) * 128, n0 = (swz % gx) * 64;
    int wr = w >> 1, wc = w & 1;
    int kq = lane >> 4, rr = lane & 15;
    const int K = D_INNER;

    f32x4 acc[4][2];
    #pragma unroll
    for (int i = 0; i < 4; i++)
        #pragma unroll
        for (int j = 0; j < 2; j++) acc[i][j] = (f32x4){0.f,0.f,0.f,0.f};

    const char* Ab = (const char*)A;
    const char* Bb = (const char*)Bw;
    char* AsB = (char*)As;
    char* BsB = (char*)Bs;

    int cA0 = tid, cA1 = tid + 256;
    int rA0 = cA0 >> 2, qA0 = (cA0 & 3) ^ ((rA0 >> 1) & 3);
    int rA1 = cA1 >> 2, qA1 = (cA1 & 3) ^ ((rA1 >> 1) & 3);
    int rB = tid >> 2,  qB  = (tid & 3) ^ ((rB >> 1) & 3);
    int sw = (kq ^ ((rr >> 1) & 3)) * 16;

    for (int k0 = 0; k0 < K; k0 += 32) {
        __builtin_amdgcn_global_load_lds(
            (const __attribute__((address_space(1))) unsigned int*)(Ab + ((size_t)(m0+rA0)*K + k0 + qA0*8)*2),
            (__attribute__((address_space(3))) unsigned int*)(AsB + cA0*16), 16, 0, 0);
        __builtin_amdgcn_global_load_lds(
            (const __attribute__((address_space(1))) unsigned int*)(Ab + ((size_t)(m0+rA1)*K + k0 + qA1*8)*2),
            (__attribute__((address_space(3))) unsigned int*)(AsB + cA1*16), 16, 0, 0);
        __builtin_amdgcn_global_load_lds(
            (const __attribute__((address_space(1))) unsigned int*)(Bb + ((size_t)(n0+rB)*K + k0 + qB*8)*2),
            (__attribute__((address_space(3))) unsigned int*)(BsB + tid*16), 16, 0, 0);
        __syncthreads();

        bf16x8 af[4], bfr[2];
        #pragma unroll
        for (int mi = 0; mi < 4; mi++) af[mi]  = *(const bf16x8*)(AsB + (wr*64 + mi*16 + rr)*64 + sw);
        #pragma unroll
        for (int ni = 0; ni < 2; ni++) bfr[ni] = *(const bf16x8*)(BsB + (wc*32 + ni*16 + rr)*64 + sw);
        #pragma unroll
        for (int mi = 0; mi < 4; mi++)
            #pragma unroll
            for (int ni = 0; ni < 2; ni++)
                acc[mi][ni] = __builtin_amdgcn_mfma_f32_16x16x32_bf16(af[mi], bfr[ni], acc[mi][ni], 0, 0, 0);
        __syncthreads();
    }

    #pragma unroll
    for (int mi = 0; mi < 4; mi++) {
        #pragma unroll
        for (int ni = 0; ni < 2; ni++) {
            #pragma unroll
            for (int r = 0; r < 4; r++) {
                int row = m0 + wr*64 + mi*16 + kq*4 + r;
                int col = n0 + wc*32 + ni*16 + rr;
                size_t o = (size_t)row*D_MODEL + col;
                C[o] = acc[mi][ni][r] + C[o];   // h holds the residual
            }
        }
    }
}

// ---------------------------------------------------------------- xproj MFMA: partials, split-K (no atomics)
__global__ __launch_bounds__(256) void gemm_xproj(const __hip_bfloat16* __restrict__ A,
                                                  const __hip_bfloat16* __restrict__ W,
                                                  float* __restrict__ P) {
    __shared__ __align__(16) __hip_bfloat16 As[64*64];
    __shared__ __align__(16) __hip_bfloat16 Bs[96*64];
    int tid = threadIdx.x, lane = tid & 63, w = tid >> 6;
    int m0 = blockIdx.x * 64;
    int k0 = blockIdx.y * (D_INNER / KSPLIT);
    int kq = lane >> 4, rr = lane & 15;
    f32x4 acc[5];
    #pragma unroll
    for (int i = 0; i < 5; i++) acc[i] = (f32x4){0.f,0.f,0.f,0.f};
    const char* Ab = (const char*)A;
    const char* Wb = (const char*)W;
    char* AsB = (char*)As;
    char* BsB = (char*)Bs;

    for (int kk = k0; kk < k0 + D_INNER/KSPLIT; kk += 64) {
        #pragma unroll
        for (int cA = 0; cA < 2; cA++) {
            int idx = cA*256 + tid;
            int r = idx >> 3, q = (idx & 7) ^ (r & 7);
            __builtin_amdgcn_global_load_lds(
                (const __attribute__((address_space(1))) unsigned int*)(Ab + ((size_t)(m0+r)*D_INNER + kk + q*8)*2),
                (__attribute__((address_space(3))) unsigned int*)(AsB + idx*16), 16, 0, 0);
        }
        #pragma unroll
        for (int cB = 0; cB < 3; cB++) {
            int idx = cB*256 + tid;
            int r = idx >> 3, q = (idx & 7) ^ (r & 7);
            int rs = r < XN ? r : XN-1;
            __builtin_amdgcn_global_load_lds(
                (const __attribute__((address_space(1))) unsigned int*)(Wb + ((size_t)rs*D_INNER + kk + q*8)*2),
                (__attribute__((address_space(3))) unsigned int*)(BsB + idx*16), 16, 0, 0);
        }
        __syncthreads();
        #pragma unroll
        for (int kh = 0; kh < 2; kh++) {
            bf16x8 a = *(const bf16x8*)(AsB + (w*16 + rr)*128 + (((kh*4 + kq) ^ (rr & 7)))*16);
            #pragma unroll
            for (int ni = 0; ni < 5; ni++) {
                bf16x8 b = *(const bf16x8*)(BsB + (ni*16 + rr)*128 + (((kh*4 + kq) ^ (rr & 7)))*16);
                acc[ni] = __builtin_amdgcn_mfma_f32_16x16x32_bf16(a, b, acc[ni], 0, 0, 0);
            }
        }
        __syncthreads();
    }
    float* Cp = P + (size_t)blockIdx.y * ROWS * XN;
    #pragma unroll
    for (int ni = 0; ni < 5; ni++)
        #pragma unroll
        for (int r = 0; r < 4; r++) {
            int row = m0 + w*16 + kq*4 + r;
            int col = ni*16 + rr;
            Cp[(size_t)row*XN + col] = acc[ni][r];
        }
}

// reduce partials -> xdbl f32 (80 cols) + xdbl_bf (first 48 cols, 64-col zero-padded)
__global__ __launch_bounds__(256) void xproj_reduce(const float* __restrict__ P,
                                                    float* __restrict__ xdbl,
                                                    __hip_bfloat16* __restrict__ xdbl_bf) {
    int idx = blockIdx.x*256 + threadIdx.x;      // ROWS*96
    int col = idx % 96, row = idx / 96;
    if (row >= ROWS) return;
    const size_t RX = (size_t)ROWS*XN;
    if (col < XN) {
        size_t o = (size_t)row*XN + col;
        float s = P[o] + P[RX + o] + P[2*RX + o] + P[3*RX + o];
        xdbl[o] = s;
        if (col < DT_RANK) xdbl_bf[(size_t)row*64 + col] = __float2bfloat16(s);
    } else {
        // col 80..95 -> zero-pad bf16 cols 48..63
        xdbl_bf[(size_t)row*64 + col - 32] = __float2bfloat16(0.f);
    }
}

// ---------------------------------------------------------------- depthwise causal conv + SiLU (bf16 in/out, x8 vec)
__global__ __launch_bounds__(256) void dwconv_silu(const __hip_bfloat16* __restrict__ xs,
                                                   const float* __restrict__ cw,
                                                   const float* __restrict__ cb,
                                                   __hip_bfloat16* __restrict__ u_bf) {
    int idx = blockIdx.x*256 + threadIdx.x;      // ROWS * D_INNER/8
    int dg = idx % (D_INNER/8);
    int t  = idx / (D_INNER/8);
    if (t >= ROWS) return;
    int d0 = dg*8;
    int l = t & 511, b = t >> 9;
    bf16x8 rows[K_CONV];
    #pragma unroll
    for (int k = 0; k < K_CONV; k++) {
        int ll = l - (K_CONV-1) + k;
        if (ll >= 0) rows[k] = *(const bf16x8*)(xs + ((size_t)(b*LSEQ + ll))*D_INNER + d0);
        else { bf16x8 z = {}; rows[k] = z; }
    }
    bf16x8 outv;
    #pragma unroll
    for (int j = 0; j < 8; j++) {
        int d = d0 + j;
        const float4 w4 = *(const float4*)(cw + d*K_CONV);
        float acc = cb[d]
                  + (float)rows[0][j]*w4.x + (float)rows[1][j]*w4.y
                  + (float)rows[2][j]*w4.z + (float)rows[3][j]*w4.w;
        float v = acc / (1.f + __expf(-acc));
        outv[j] = (__bf16)v;
    }
    *(bf16x8*)(u_bf + (size_t)t*D_INNER + d0) = outv;
}

// ---------------------------------------------------------------- selective scan, 3-phase chunked (NC=16, CL=32)
// delta_blk, gres_blk: blocked [b][t/16][d][16] f32.  u: bf16 row-major.
// xfin: [b][c][n][d] transposed.  B/C: wave-uniform from xdbl.
__global__ __launch_bounds__(256) void scan_p1(const __hip_bfloat16* __restrict__ u,
                                               const float* __restrict__ delta_blk,
                                               const float* __restrict__ xdbl,
                                               const float* __restrict__ A_log,
                                               float* __restrict__ xfin,
                                               float* __restrict__ sumdlt) {
    int d = blockIdx.x*256 + threadIdx.x;
    int c = blockIdx.y, b = blockIdx.z;
    int l0 = c*CL;
    float A2[N_STATE], xs[N_STATE];
    const float* al = A_log + d*N_STATE;
    #pragma unroll
    for (int n = 0; n < N_STATE; n++) {
        A2[n] = -__expf(al[n]) * LOG2E;
        xs[n] = 0.f;
    }
    const __hip_bfloat16* pu = u + (size_t)(b*LSEQ + l0)*D_INNER + d;
    const float* pB = xdbl + (size_t)(b*LSEQ + l0)*XN + DT_RANK;   // wave-uniform
    float sd = 0.f;
    #pragma unroll
    for (int tt = 0; tt < 2; tt++) {
        const float* db = delta_blk + ((size_t)(b*NTILE + (l0>>4) + tt)*D_INNER + d)*16;
        float dl[16];
        #pragma unroll
        for (int q = 0; q < 4; q++) {
            f32x4 v = *(const f32x4*)(db + q*4);
            dl[q*4+0]=v[0]; dl[q*4+1]=v[1]; dl[q*4+2]=v[2]; dl[q*4+3]=v[3];
        }
        #pragma unroll
        for (int i = 0; i < 16; i++) {
            float dlt = dl[i];
            float uu = __bfloat162float(*pu); pu += D_INNER;
            float du = dlt*uu;
            sd += dlt;
            #pragma unroll
            for (int n = 0; n < N_STATE; n++)
                xs[n] = fexp2(dlt*A2[n])*xs[n] + du*pB[n];
            pB += XN;
        }
    }
    float* px = xfin + (size_t)((b*NC + c)*N_STATE)*D_INNER + d;
    #pragma unroll
    for (int n = 0; n < N_STATE; n++) px[n*D_INNER] = xs[n];
    sumdlt[(size_t)(b*NC + c)*D_INNER + d] = sd;
}

// in-place: carry for chunk c stored into xfin slot (c-1). chunk 0 carry == 0.
__global__ __launch_bounds__(256) void scan_p2(float* __restrict__ xfin,
                                               const float* __restrict__ sumdlt,
                                               const float* __restrict__ A_log) {
    int idx = blockIdx.x*256 + threadIdx.x;
    int d = idx % D_INNER;
    int r = idx / D_INNER;
    int n = r & 15;
    int b = r >> 4;
    float A2 = -__expf(A_log[d*N_STATE + n]) * LOG2E;
    float cr = 0.f;
    for (int c = 1; c < NC; c++) {
        size_t jp = (size_t)(b*NC + c - 1);
        float xf = xfin[(jp*N_STATE + n)*D_INNER + d];
        float s  = sumdlt[jp*D_INNER + d];
        cr = fexp2(A2 * s) * cr + xf;
        xfin[(jp*N_STATE + n)*D_INNER + d] = cr;
    }
}

__global__ __launch_bounds__(256) void scan_p3(const __hip_bfloat16* __restrict__ u,
                                               const float* __restrict__ delta_blk,
                                               const float* __restrict__ gres_blk,
                                               const float* __restrict__ xdbl,
                                               const float* __restrict__ A_log,
                                               const float* __restrict__ Dp,
                                               const float* __restrict__ carry,
                                               __hip_bfloat16* __restrict__ ygate) {
    int d = blockIdx.x*256 + threadIdx.x;
    int c = blockIdx.y, b = blockIdx.z;
    int l0 = c*CL;
    float A2[N_STATE], xs[N_STATE];
    const float* al = A_log + d*N_STATE;
    #pragma unroll
    for (int n = 0; n < N_STATE; n++) A2[n] = -__expf(al[n]) * LOG2E;
    if (c == 0) {
        #pragma unroll
        for (int n = 0; n < N_STATE; n++) xs[n] = 0.f;
    } else {
        const float* pc = carry + (size_t)((b*NC + c - 1)*N_STATE)*D_INNER + d;
        #pragma unroll
        for (int n = 0; n < N_STATE; n++) xs[n] = pc[n*D_INNER];
    }
    float Dv = Dp[d];
    const __hip_bfloat16* pu = u + (size_t)(b*LSEQ + l0)*D_INNER + d;
    const float* pB = xdbl + (size_t)(b*LSEQ + l0)*XN + DT_RANK;   // wave-uniform
    __hip_bfloat16* py = ygate + (size_t)(b*LSEQ + l0)*D_INNER + d;
    #pragma unroll
    for (int tt = 0; tt < 2; tt++) {
        size_t tb = (size_t)(b*NTILE + (l0>>4) + tt)*D_INNER + d;
        const float* db = delta_blk + tb*16;
        const float* gb = gres_blk  + tb*16;
        float dl[16], gr[16];
        #pragma unroll
        for (int q = 0; q < 4; q++) {
            f32x4 v = *(const f32x4*)(db + q*4);
            dl[q*4+0]=v[0]; dl[q*4+1]=v[1]; dl[q*4+2]=v[2]; dl[q*4+3]=v[3];
            f32x4 g = *(const f32x4*)(gb + q*4);
            gr[q*4+0]=g[0]; gr[q*4+1]=g[1]; gr[q*4+2]=g[2]; gr[q*4+3]=g[3];
        }
        #pragma unroll
        for (int i = 0; i < 16; i++) {
            float dlt = dl[i];
            float uu = __bfloat162float(*pu); pu += D_INNER;
            float du = dlt*uu;
            float acc = 0.f;
            #pragma unroll
            for (int n = 0; n < N_STATE; n++) {
                xs[n] = fexp2(dlt*A2[n])*xs[n] + du*pB[n];
                acc += xs[n]*pB[N_STATE + n];
            }
            pB += XN;
            float y = acc + uu*Dv;
            *py = __float2bfloat16(y * gr[i]); py += D_INNER;
        }
    }
}

// ---------------------------------------------------------------- final norm + head + de-norm
__global__ __launch_bounds__(256) void final_kernel(const float* __restrict__ h,
                                                    const float* __restrict__ fnw,
                                                    const float* __restrict__ out_w,
                                                    const float* __restrict__ mean,
                                                    const float* __restrict__ stdv,
                                                    float* __restrict__ out) {
    int bid = blockIdx.x;
    int b = bid / PRED_LEN, lo = bid % PRED_LEN;
    int l = LSEQ - PRED_LEN + lo;
    const float* row = h + ((size_t)(b*LSEQ + l))*D_MODEL;
    __shared__ float tmp[4];
    float ss = 0.f;
    for (int k = threadIdx.x; k < D_MODEL; k += 256) { float v = row[k]; ss += v*v; }
    ss = block_sum(ss, tmp);
    float inv = rsqrtf(ss / (float)D_MODEL + EPSV);
    float acc[C_OUT] = {};
    for (int k = threadIdx.x; k < D_MODEL; k += 256) {
        float hn = row[k]*fnw[k];
        #pragma unroll
        for (int c = 0; c < C_OUT; c++) acc[c] += hn*out_w[c*D_MODEL + k];
    }
    #pragma unroll
    for (int c = 0; c < C_OUT; c++) {
        float s = block_sum(acc[c], tmp);
        if (threadIdx.x == 0)
            out[((size_t)(b*PRED_LEN + lo))*C_OUT + c] = s*inv*stdv[b*ENC_IN + c] + mean[b*ENC_IN + c];
    }
}

// ---------------------------------------------------------------- launch
extern "C" void kernel_launch(void* const* d_in, const int* in_sizes, int n_in,
                              void* d_out, int out_size, void* d_ws, size_t ws_size,
                              hipStream_t stream) {
    const float* x        = (const float*)d_in[0];
    const float* token_w  = (const float*)d_in[1];
    const float* time_w   = (const float*)d_in[2];
    const float* norm_w   = (const float*)d_in[3];
    const float* in_w     = (const float*)d_in[4];
    const float* conv_w   = (const float*)d_in[5];
    const float* conv_b   = (const float*)d_in[6];
    const float* xproj_w  = (const float*)d_in[7];
    const float* dtproj_w = (const float*)d_in[8];
    const float* dtproj_b = (const float*)d_in[9];
    const float* A_log    = (const float*)d_in[10];
    const float* Dp       = (const float*)d_in[11];
    const float* outproj_w= (const float*)d_in[12];
    const float* final_nw = (const float*)d_in[13];
    const float* out_w    = (const float*)d_in[14];
    float* out = (float*)d_out;

    float* ws   = (float*)d_ws;
    float* mean = ws;
    float* stdv = ws + 64;
    float* h    = ws + 128;                            // ROWS*D_MODEL
    float* gres = h    + (size_t)ROWS*D_MODEL;         // blocked silu(res), f32
    float* delta= gres + (size_t)ROWS*D_INNER;         // blocked f32
    float* xdbl = delta+ (size_t)ROWS*D_INNER;         // ROWS*80 f32
    float* sumd = xdbl + (size_t)ROWS*XN;              // BSZ*NC*D_INNER
    float* xfin = sumd + (size_t)BSZ*NC*D_INNER;       // BSZ*NC*N_STATE*D_INNER
    float* pout = xfin + (size_t)BSZ*NC*D_INNER*N_STATE; // KSPLIT*ROWS*XN partials
    float* fend = pout + (size_t)KSPLIT*ROWS*XN;
    __hip_bfloat16* xn_bf  = (__hip_bfloat16*)fend;
    __hip_bfloat16* xs_bf  = xn_bf + (size_t)ROWS*D_MODEL;
    __hip_bfloat16* u_bf   = xs_bf + (size_t)ROWS*D_INNER;
    __hip_bfloat16* ygate  = u_bf  + (size_t)ROWS*D_INNER;
    __hip_bfloat16* xdbl_bf= ygate + (size_t)ROWS*D_INNER;           // ROWS x 64
    __hip_bfloat16* inw_bf = xdbl_bf+ (size_t)ROWS*64;
    __hip_bfloat16* outw_bf= inw_bf + (size_t)E_LAYERS*2*D_INNER*D_MODEL;
    __hip_bfloat16* xpw_bf = outw_bf+ (size_t)E_LAYERS*D_MODEL*D_INNER;
    __hip_bfloat16* dtw_bf = xpw_bf + (size_t)E_LAYERS*XN*D_INNER;   // E_LAYERS x 1536 x 64

    // convert all weights to bf16 (single launch)
    {
        const int NT = E_LAYERS*2*D_INNER*D_MODEL + E_LAYERS*D_MODEL*D_INNER
                     + E_LAYERS*XN*D_INNER + E_LAYERS*D_INNER*64;
        cvt_all<<<(NT+255)/256, 256, 0, stream>>>(in_w, outproj_w, xproj_w, dtproj_w,
                                                  inw_bf, outw_bf, xpw_bf, dtw_bf);
    }

    stats_kernel<<<BSZ*ENC_IN, 256, 0, stream>>>(x, mean, stdv);
    embed_kernel<<<ROWS, 256, 0, stream>>>(x, token_w, time_w, mean, stdv, h);

    for (int e = 0; e < E_LAYERS; e++) {
        rmsnorm_bf16<<<ROWS, 256, 0, stream>>>(h, norm_w + e*D_MODEL, xn_bf);
        gemm_mfma<3><<<dim3(2*D_INNER/128, ROWS/128), 256, 0, stream>>>(
            xn_bf, inw_bf + (size_t)e*2*D_INNER*D_MODEL, nullptr, D_MODEL,
            nullptr, gres, xs_bf);
        dwconv_silu<<<(ROWS*(D_INNER/8) + 255)/256, 256, 0, stream>>>(
            xs_bf, conv_w + (size_t)e*D_INNER*K_CONV, conv_b + e*D_INNER, u_bf);
        gemm_xproj<<<dim3(ROWS/64, KSPLIT), 256, 0, stream>>>(
            u_bf, xpw_bf + (size_t)e*XN*D_INNER, pout);
        xproj_reduce<<<(ROWS*96 + 255)/256, 256, 0, stream>>>(pout, xdbl, xdbl_bf);
        gemm_mfma<1><<<dim3(D_INNER/128, ROWS/128), 256, 0, stream>>>(
            xdbl_bf, dtw_bf + (size_t)e*D_INNER*64, delta, 64,
            dtproj_b + e*D_INNER, nullptr, nullptr);
        const float* Alog_e = A_log + (size_t)e*D_INNER*N_STATE;
        scan_p1<<<dim3(D_INNER/256, NC, BSZ), 256, 0, stream>>>(
            u_bf, delta, xdbl, Alog_e, xfin, sumd);
        scan_p2<<<(BSZ*D_INNER*N_STATE)/256, 256, 0, stream>>>(
            xfin, sumd, Alog_e);
        scan_p3<<<dim3(D_INNER/256, NC, BSZ), 256, 0, stream>>>(
            u_bf, delta, gres, xdbl, Alog_e, Dp + (size_t)e*D_INNER, xfin, ygate);
        gemm_outproj<<<dim3(D_MODEL/64, ROWS/128), 256, 0, stream>>>(
            ygate, outw_bf + (size_t)e*D_MODEL*D_INNER, h);
    }

    final_kernel<<<BSZ*PRED_LEN, 256, 0, stream>>>(h, final_nw, out_w, mean, stdv, out);
}